// Round 1
// baseline (1611.674 us; speedup 1.0000x reference)
//
#include <hip/hip_runtime.h>
#include <hip/hip_bf16.h>
#include <math.h>

// Problem constants (from reference): x [8,256,64,64] fp32, N = 64*64 = 4096.
#define B_   8
#define C_   256
#define CQK_ 32
#define N_   4096
#define QSCALE 0.17677669529663687f   // 1/sqrt(C/8) = 1/sqrt(32), folded into q

// ---------------------------------------------------------------------------
// Kernel 1: fused QKV projection (1x1 conv == channel matmul), fp32.
// grid (N/64, B), block 256. LDS x-tile [256 c][64 n]; each thread computes a
// 4-row x 4-col register tile; 5 chunks of 64 rows cover the 320 output rows
// (32 q + 32 k + 256 v). q is pre-scaled by 1/sqrt(32).
// ---------------------------------------------------------------------------
__global__ __launch_bounds__(256) void qkv_proj_k(
    const float* __restrict__ x,
    const float* __restrict__ Wq, const float* __restrict__ bq,
    const float* __restrict__ Wk, const float* __restrict__ bk,
    const float* __restrict__ Wv, const float* __restrict__ bv,
    float* __restrict__ q, float* __restrict__ k, float* __restrict__ v)
{
    const int b  = blockIdx.y;
    const int n0 = blockIdx.x * 64;
    const int t  = threadIdx.x;

    __shared__ float4 xs4[C_][16];   // xs4[c][i4] = x[b][c][n0 + 4*i4 .. +3]

    const float* xb = x + (size_t)b * C_ * N_ + n0;
    #pragma unroll
    for (int r = 0; r < 16; ++r) {
        int idx = r * 256 + t;            // 0..4095, coalesced along n
        int c = idx >> 4, i4 = idx & 15;
        xs4[c][i4] = *reinterpret_cast<const float4*>(xb + (size_t)c * N_ + i4 * 4);
    }
    __syncthreads();

    const int og = t >> 4;   // 0..15: row group (4 rows each)
    const int tn = t & 15;   // 0..15: col group (4 n each)

    for (int chunk = 0; chunk < 5; ++chunk) {
        const int r0 = chunk * 64 + og * 4;   // combined row 0..319, 4-aligned
        const float* Wb; const float* bb; float* ob; int rr; float scl;
        if (r0 < 32)      { Wb = Wq; bb = bq; ob = q + (size_t)b * CQK_ * N_; rr = r0;      scl = QSCALE; }
        else if (r0 < 64) { Wb = Wk; bb = bk; ob = k + (size_t)b * CQK_ * N_; rr = r0 - 32; scl = 1.0f;   }
        else              { Wb = Wv; bb = bv; ob = v + (size_t)b * C_  * N_;  rr = r0 - 64; scl = 1.0f;   }

        float4 acc[4];
        acc[0] = acc[1] = acc[2] = acc[3] = make_float4(0.f, 0.f, 0.f, 0.f);

        #pragma unroll 4
        for (int c4 = 0; c4 < 64; ++c4) {
            const float4 xv0 = xs4[c4 * 4 + 0][tn];
            const float4 xv1 = xs4[c4 * 4 + 1][tn];
            const float4 xv2 = xs4[c4 * 4 + 2][tn];
            const float4 xv3 = xs4[c4 * 4 + 3][tn];
            #pragma unroll
            for (int j = 0; j < 4; ++j) {
                const float4 wv = *reinterpret_cast<const float4*>(Wb + (size_t)(rr + j) * C_ + c4 * 4);
                acc[j].x += wv.x * xv0.x + wv.y * xv1.x + wv.z * xv2.x + wv.w * xv3.x;
                acc[j].y += wv.x * xv0.y + wv.y * xv1.y + wv.z * xv2.y + wv.w * xv3.y;
                acc[j].z += wv.x * xv0.z + wv.y * xv1.z + wv.z * xv2.z + wv.w * xv3.z;
                acc[j].w += wv.x * xv0.w + wv.y * xv1.w + wv.z * xv2.w + wv.w * xv3.w;
            }
        }
        #pragma unroll
        for (int j = 0; j < 4; ++j) {
            const float bias = bb[rr + j];
            float4 o;
            o.x = (acc[j].x + bias) * scl;
            o.y = (acc[j].y + bias) * scl;
            o.z = (acc[j].z + bias) * scl;
            o.w = (acc[j].w + bias) * scl;
            *reinterpret_cast<float4*>(ob + (size_t)(rr + j) * N_ + n0 + tn * 4) = o;
        }
    }
}

// ---------------------------------------------------------------------------
// Kernel 2: flash-style attention + epilogue (gamma*out + x), fp32.
// grid (N/64, B), block 256. Per block: 64 queries (i-tile), loop j-tiles of 64.
// Score phase: thread tile 4i x 4jj from LDS q/k tiles; online softmax with
// per-row (m,l) state in LDS (rows partitioned per wave -> race-free).
// PV phase: thread owns 4 c x 16 i accumulators; v read straight from global
// (v[b] = 4MB, L2/L3 resident); P broadcast from LDS.
// ---------------------------------------------------------------------------
__global__ __launch_bounds__(256) void attn_k(
    const float* __restrict__ q, const float* __restrict__ k, const float* __restrict__ v,
    const float* __restrict__ x, const float* __restrict__ gamma,
    float* __restrict__ out)
{
    const int b  = blockIdx.y;
    const int i0 = blockIdx.x * 64;
    const int t  = threadIdx.x;

    __shared__ float  qs[CQK_][64];     // q[d][i]   (q memory layout is [d][n])
    __shared__ float  ks[CQK_][64];     // k[d][jj]
    __shared__ float4 sP[64][16];       // P[i][jj4] as float4 over jj
    __shared__ float  m_s[64], l_s[64], f_s[64];

    const float* qb = q + (size_t)b * CQK_ * N_ + i0;
    #pragma unroll
    for (int r = 0; r < 8; ++r) {
        int idx = r * 256 + t;          // 0..2047
        int d = idx >> 6, ii = idx & 63;
        qs[d][ii] = qb[(size_t)d * N_ + ii];
    }
    if (t < 64) { m_s[t] = -INFINITY; l_s[t] = 0.f; }

    float acc[4][16];                   // [cc][ii]
    #pragma unroll
    for (int cc = 0; cc < 4; ++cc)
        #pragma unroll
        for (int ii = 0; ii < 16; ++ii) acc[cc][ii] = 0.f;

    __syncthreads();

    const int ti = t >> 4, tj = t & 15;   // score mapping: rows ti*4.., cols tj*4..
    const int cg = t & 63, ig = t >> 6;   // PV mapping: c = cg*4+cc, i = ig*16+ii
    const float* kb = k + (size_t)b * CQK_ * N_;
    const float* vb = v + (size_t)b * C_  * N_;

    for (int j0 = 0; j0 < N_; j0 += 64) {
        // ---- stage K tile ----
        #pragma unroll
        for (int r = 0; r < 8; ++r) {
            int idx = r * 256 + t;
            int d = idx >> 6, jj = idx & 63;
            ks[d][jj] = kb[(size_t)d * N_ + j0 + jj];
        }
        __syncthreads();

        // ---- scores: s[ii2][jc] = sum_d q[d][i]*k[d][jj], pre-scaled q ----
        float s[4][4];
        #pragma unroll
        for (int a = 0; a < 4; ++a)
            #pragma unroll
            for (int c2 = 0; c2 < 4; ++c2) s[a][c2] = 0.f;

        #pragma unroll 8
        for (int d = 0; d < CQK_; ++d) {
            const float4 qv = *reinterpret_cast<const float4*>(&qs[d][ti * 4]);
            const float4 kv = *reinterpret_cast<const float4*>(&ks[d][tj * 4]);
            s[0][0] += qv.x * kv.x; s[0][1] += qv.x * kv.y; s[0][2] += qv.x * kv.z; s[0][3] += qv.x * kv.w;
            s[1][0] += qv.y * kv.x; s[1][1] += qv.y * kv.y; s[1][2] += qv.y * kv.z; s[1][3] += qv.y * kv.w;
            s[2][0] += qv.z * kv.x; s[2][1] += qv.z * kv.y; s[2][2] += qv.z * kv.z; s[2][3] += qv.z * kv.w;
            s[3][0] += qv.w * kv.x; s[3][1] += qv.w * kv.y; s[3][2] += qv.w * kv.z; s[3][3] += qv.w * kv.w;
        }

        // ---- online softmax (rows exclusive per wave: wave w owns i in [w*16, w*16+16)) ----
        #pragma unroll
        for (int ii2 = 0; ii2 < 4; ++ii2) {
            const int i = ti * 4 + ii2;
            float mx = fmaxf(fmaxf(s[ii2][0], s[ii2][1]), fmaxf(s[ii2][2], s[ii2][3]));
            #pragma unroll
            for (int off = 1; off < 16; off <<= 1) mx = fmaxf(mx, __shfl_xor(mx, off));
            const float m_old = m_s[i];
            const float m_new = fmaxf(m_old, mx);
            const float p0 = __expf(s[ii2][0] - m_new);
            const float p1 = __expf(s[ii2][1] - m_new);
            const float p2 = __expf(s[ii2][2] - m_new);
            const float p3 = __expf(s[ii2][3] - m_new);
            float sum = (p0 + p1) + (p2 + p3);
            #pragma unroll
            for (int off = 1; off < 16; off <<= 1) sum += __shfl_xor(sum, off);
            sP[i][tj] = make_float4(p0, p1, p2, p3);
            if (tj == 0) {
                const float f = __expf(m_old - m_new);
                m_s[i] = m_new;
                l_s[i] = l_s[i] * f + sum;
                f_s[i] = f;
            }
        }
        __syncthreads();

        // ---- rescale accumulators ----
        #pragma unroll
        for (int ii = 0; ii < 16; ++ii) {
            const float f = f_s[ig * 16 + ii];
            acc[0][ii] *= f; acc[1][ii] *= f; acc[2][ii] *= f; acc[3][ii] *= f;
        }

        // ---- PV accumulate: acc[cc][ii] += sum_jj v[c][jj] * P[i][jj] ----
        #pragma unroll 2
        for (int jj4 = 0; jj4 < 16; ++jj4) {
            const float* vp = vb + (size_t)(cg * 4) * N_ + j0 + jj4 * 4;
            const float4 v0 = *reinterpret_cast<const float4*>(vp);
            const float4 v1 = *reinterpret_cast<const float4*>(vp + N_);
            const float4 v2 = *reinterpret_cast<const float4*>(vp + 2 * (size_t)N_);
            const float4 v3 = *reinterpret_cast<const float4*>(vp + 3 * (size_t)N_);
            #pragma unroll
            for (int ii = 0; ii < 16; ++ii) {
                const float4 p = sP[ig * 16 + ii][jj4];   // wave-uniform broadcast
                acc[0][ii] += v0.x * p.x + v0.y * p.y + v0.z * p.z + v0.w * p.w;
                acc[1][ii] += v1.x * p.x + v1.y * p.y + v1.z * p.z + v1.w * p.w;
                acc[2][ii] += v2.x * p.x + v2.y * p.y + v2.z * p.z + v2.w * p.w;
                acc[3][ii] += v3.x * p.x + v3.y * p.y + v3.z * p.z + v3.w * p.w;
            }
        }
        __syncthreads();
    }

    // ---- epilogue: out = gamma * (acc / l) + x ----
    const float g = gamma[0];
    float linv[16];
    #pragma unroll
    for (int ii = 0; ii < 16; ++ii) linv[ii] = 1.0f / l_s[ig * 16 + ii];

    const float* xb = x   + (size_t)b * C_ * N_ + i0 + ig * 16;
    float*       ob = out + (size_t)b * C_ * N_ + i0 + ig * 16;
    #pragma unroll
    for (int cc = 0; cc < 4; ++cc) {
        const int c = cg * 4 + cc;
        #pragma unroll
        for (int ii4 = 0; ii4 < 4; ++ii4) {
            const float4 xv = *reinterpret_cast<const float4*>(xb + (size_t)c * N_ + ii4 * 4);
            float4 o;
            o.x = g * acc[cc][ii4 * 4 + 0] * linv[ii4 * 4 + 0] + xv.x;
            o.y = g * acc[cc][ii4 * 4 + 1] * linv[ii4 * 4 + 1] + xv.y;
            o.z = g * acc[cc][ii4 * 4 + 2] * linv[ii4 * 4 + 2] + xv.z;
            o.w = g * acc[cc][ii4 * 4 + 3] * linv[ii4 * 4 + 3] + xv.w;
            *reinterpret_cast<float4*>(ob + (size_t)c * N_ + ii4 * 4) = o;
        }
    }
}

// ---------------------------------------------------------------------------
// Launch. Workspace layout (fp32): q [8,32,4096] | k [8,32,4096] | v [8,256,4096]
// = 4 MB + 4 MB + 32 MB = 40 MB required in d_ws.
// ---------------------------------------------------------------------------
extern "C" void kernel_launch(void* const* d_in, const int* in_sizes, int n_in,
                              void* d_out, int out_size, void* d_ws, size_t ws_size,
                              hipStream_t stream) {
    const float* x     = (const float*)d_in[0];
    const float* Wq    = (const float*)d_in[1];
    const float* bq    = (const float*)d_in[2];
    const float* Wk    = (const float*)d_in[3];
    const float* bk    = (const float*)d_in[4];
    const float* Wv    = (const float*)d_in[5];
    const float* bv    = (const float*)d_in[6];
    const float* gamma = (const float*)d_in[7];
    float* out = (float*)d_out;

    float* q = (float*)d_ws;
    float* k = q + (size_t)B_ * CQK_ * N_;
    float* v = k + (size_t)B_ * CQK_ * N_;

    dim3 grid(N_ / 64, B_);
    qkv_proj_k<<<grid, 256, 0, stream>>>(x, Wq, bq, Wk, bk, Wv, bv, q, k, v);
    attn_k<<<grid, 256, 0, stream>>>(q, k, v, x, gamma, out);
}

// Round 2
// 316.819 us; speedup vs baseline: 5.0870x; 5.0870x over previous
//
#include <hip/hip_runtime.h>
#include <hip/hip_bf16.h>
#include <math.h>

// Problem constants: x [8,256,64,64] fp32, N = 4096, C = 256, Cqk = 32.
#define B_   8
#define C_   256
#define N_   4096
#define QSCALE 0.17677669529663687f   // 1/sqrt(32), folded into q at projection

typedef __attribute__((ext_vector_type(8))) short bf16x8;   // 8 bf16 = 4 VGPRs
typedef __attribute__((ext_vector_type(4))) float f32x4;

__device__ __forceinline__ unsigned short bfu(float f) {
    __hip_bfloat16 h = __float2bfloat16(f);
    return __builtin_bit_cast(unsigned short, h);
}
__device__ __forceinline__ unsigned pack2(float lo, float hi) {
    return ((unsigned)bfu(hi) << 16) | (unsigned)bfu(lo);
}
__device__ __forceinline__ bf16x8 cvt8(const float* p) {
    const float4 a = *reinterpret_cast<const float4*>(p);
    const float4 b = *reinterpret_cast<const float4*>(p + 4);
    bf16x8 r;
    r[0] = (short)bfu(a.x); r[1] = (short)bfu(a.y);
    r[2] = (short)bfu(a.z); r[3] = (short)bfu(a.w);
    r[4] = (short)bfu(b.x); r[5] = (short)bfu(b.y);
    r[6] = (short)bfu(b.z); r[7] = (short)bfu(b.w);
    return r;
}

// ---------------------------------------------------------------------------
// Kernel 1: QKV projection via MFMA. grid (64, 8), block 256 (4 waves).
// LDS: xT [64 n][256 c] bf16, 16B-slot XOR-swizzled (slot' = slot ^ (n&7)).
// Per wave: v-slice D[o][n] = Wv·X (o range w*64..+64, 16 frags) and one
// q/k job D[n][o] = X^T·W^T (2 o-tiles x 2 n-tiles). K = 256 in 8 steps.
// Outputs: q,k as [b][n][32] bf16 (q pre-scaled), v as [b][c][n] bf16.
// ---------------------------------------------------------------------------
__global__ __launch_bounds__(256, 2) void qkv_proj_mfma(
    const float* __restrict__ x,
    const float* __restrict__ Wq, const float* __restrict__ bq,
    const float* __restrict__ Wk, const float* __restrict__ bk,
    const float* __restrict__ Wv, const float* __restrict__ bv,
    unsigned short* __restrict__ q, unsigned short* __restrict__ k,
    unsigned short* __restrict__ v)
{
    const int b = blockIdx.y, n0 = blockIdx.x * 64;
    const int t = threadIdx.x;
    const int l = t & 63, w = t >> 6;
    const int li = l & 15, g = l >> 4;

    __shared__ unsigned short xT[64 * 256];   // [n][c], swizzled

    // ---- stage x -> xT (transpose + fp32->bf16) ----
    {
        const int n = t & 63;                 // lane-contiguous n: coalesced reads
        const int cq0 = t >> 6;
        const float* xb = x + ((size_t)b * C_) * N_ + n0 + n;
        #pragma unroll 4
        for (int s = 0; s < 16; ++s) {
            const int cq = cq0 + 4 * s;       // c = cq*4 .. +3
            const float f0 = xb[(size_t)(cq * 4 + 0) * N_];
            const float f1 = xb[(size_t)(cq * 4 + 1) * N_];
            const float f2 = xb[(size_t)(cq * 4 + 2) * N_];
            const float f3 = xb[(size_t)(cq * 4 + 3) * N_];
            ushort4 pk;
            pk.x = bfu(f0); pk.y = bfu(f1); pk.z = bfu(f2); pk.w = bfu(f3);
            const int byte = n * 512 + (((cq >> 1) ^ (n & 7)) << 4) + (cq & 1) * 8;
            *reinterpret_cast<ushort4*>(reinterpret_cast<char*>(xT) + byte) = pk;
        }
    }
    __syncthreads();

    // wave job for q/k: w=0: q rows n 0-31; w=1: q n 32-63; w=2/3: same for k
    const float* Wqk = (w < 2) ? Wq : Wk;
    const float* bqk = (w < 2) ? bq : bk;
    unsigned short* qk_out = (w < 2) ? q : k;
    const float qscl = (w < 2) ? QSCALE : 1.0f;
    const int mt0 = (w & 1) * 2;
    const int ov0 = w * 64;

    f32x4 accv[4][4];   // [ot][nt]  v-part D[o][n]
    f32x4 accq[2][2];   // [ot][m2]  qk-part D[n][o]
    const f32x4 z4 = {0.f, 0.f, 0.f, 0.f};
    #pragma unroll
    for (int a = 0; a < 4; ++a)
        #pragma unroll
        for (int c2 = 0; c2 < 4; ++c2) accv[a][c2] = z4;
    #pragma unroll
    for (int a = 0; a < 2; ++a)
        #pragma unroll
        for (int c2 = 0; c2 < 2; ++c2) accq[a][c2] = z4;

    #pragma unroll 2
    for (int kk = 0; kk < 8; ++kk) {
        bf16x8 xf[4];
        #pragma unroll
        for (int nt = 0; nt < 4; ++nt) {
            const int row = nt * 16 + li;
            const int byte = row * 512 + (((kk * 4 + g) ^ (row & 7)) << 4);
            xf[nt] = *reinterpret_cast<const bf16x8*>(
                reinterpret_cast<const char*>(xT) + byte);
        }
        // v-part: A = Wv[o][c] (global fp32 -> bf16), B = X[c][n] (xf)
        #pragma unroll
        for (int ot = 0; ot < 4; ++ot) {
            const bf16x8 aW = cvt8(Wv + (size_t)(ov0 + ot * 16 + li) * C_ + kk * 32 + g * 8);
            #pragma unroll
            for (int nt = 0; nt < 4; ++nt)
                accv[ot][nt] = __builtin_amdgcn_mfma_f32_16x16x32_bf16(
                    aW, xf[nt], accv[ot][nt], 0, 0, 0);
        }
        // qk-part: A = X^T[n][c] (xf), B = W^T[c][o] (global fp32 -> bf16)
        #pragma unroll
        for (int ot = 0; ot < 2; ++ot) {
            const bf16x8 bW = cvt8(Wqk + (size_t)(ot * 16 + li) * C_ + kk * 32 + g * 8);
            #pragma unroll
            for (int m2 = 0; m2 < 2; ++m2)
                accq[ot][m2] = __builtin_amdgcn_mfma_f32_16x16x32_bf16(
                    xf[mt0 + m2], bW, accq[ot][m2], 0, 0, 0);
        }
    }

    // ---- epilogue v: D[o][n], col n = li, rows o = ot*16 + 4g + r ----
    #pragma unroll
    for (int ot = 0; ot < 4; ++ot) {
        #pragma unroll
        for (int r = 0; r < 4; ++r) {
            const int o = ov0 + ot * 16 + 4 * g + r;
            const float bias = bv[o];
            #pragma unroll
            for (int nt = 0; nt < 4; ++nt) {
                const int n = nt * 16 + li;
                v[((size_t)b * C_ + o) * N_ + n0 + n] = bfu(accv[ot][nt][r] + bias);
            }
        }
    }
    // ---- epilogue q/k: D[n][o], col d = ot*16 + li, rows n = (mt0+m2)*16+4g+r ----
    #pragma unroll
    for (int ot = 0; ot < 2; ++ot) {
        const int d = ot * 16 + li;
        const float bias = bqk[d];
        #pragma unroll
        for (int m2 = 0; m2 < 2; ++m2) {
            #pragma unroll
            for (int r = 0; r < 4; ++r) {
                const int n = (mt0 + m2) * 16 + 4 * g + r;
                qk_out[((size_t)b * N_ + n0 + n) * 32 + d] = bfu((accq[ot][m2][r] + bias) * qscl);
            }
        }
    }
}

// ---------------------------------------------------------------------------
// Kernel 2: flash attention via MFMA + residual epilogue. grid (64, 8),
// block 256 (4 waves). Q-tile = 64 queries; wave w owns c-slice [w*64, +64).
// Swapped QK^T: S^T[j][i] = mfma(A=K-frag, B=Q-frag) -> softmax state is
// per-lane (col i = lane&15). K rows are PERMUTED at staging so each lane's
// S^T rows are exactly the 8 consecutive j's its PV B-frag needs: P packs
// in-lane, zero cross-lane traffic. PV: O^T[c][i] = mfma(A=V[c][j] from
// global (L2-resident), B=P^T). Online softmax with deferred 1/l.
// ---------------------------------------------------------------------------
__global__ __launch_bounds__(256, 2) void attn_mfma(
    const unsigned short* __restrict__ q, const unsigned short* __restrict__ k,
    const unsigned short* __restrict__ v,
    const float* __restrict__ x, const float* __restrict__ gamma,
    float* __restrict__ out)
{
    const int b = blockIdx.y, i0 = blockIdx.x * 64;
    const int t = threadIdx.x;
    const int l = t & 63, w = t >> 6;
    const int li = l & 15, g = l >> 4;
    const int cw0 = w * 64;

    __shared__ unsigned short kT[2][64 * 32];   // double-buffered K tile, 4 KB each

    const unsigned short* qb = q + (size_t)b * N_ * 32;
    const unsigned short* kb = k + (size_t)b * N_ * 32;
    const unsigned short* vb = v + ((size_t)b * C_) * N_;

    // Q fragments (held all kernel): B-frag for it-th 16 queries
    bf16x8 qf[4];
    #pragma unroll
    for (int it = 0; it < 4; ++it)
        qf[it] = *reinterpret_cast<const bf16x8*>(
            qb + (size_t)(i0 + it * 16 + li) * 32 + g * 8);

    f32x4 acc[4][4];   // [ct][it] : O^T[c][i]
    const f32x4 z4 = {0.f, 0.f, 0.f, 0.f};
    #pragma unroll
    for (int a = 0; a < 4; ++a)
        #pragma unroll
        for (int c2 = 0; c2 < 4; ++c2) acc[a][c2] = z4;

    float m_run[4], l_run[4];
    #pragma unroll
    for (int it = 0; it < 4; ++it) { m_run[it] = -3.0e38f; l_run[it] = 0.f; }

    // K staging constants: thread t -> LDS row jr = t>>2, slot sl = t&3.
    // Row permutation: LDS row (jt,gg,rr) holds physical j so that D-frag
    // (lane group g, reg r) of frag jt is j = (jt>>1)*32 + (jt&1)*4 + 8g + r.
    const int jr = t >> 2, sl = t & 3;
    const int jt_s = jr >> 4, gg = (jr >> 2) & 3, rr = jr & 3;
    const int jphys = (jt_s >> 1) * 32 + (jt_s & 1) * 4 + gg * 8 + rr;
    const int s_src = sl ^ (jr & 3);            // bank swizzle (content pre-swizzled)
    unsigned short* ldst0 = &kT[0][(size_t)t * 8];
    unsigned short* ldst1 = &kT[1][(size_t)t * 8];
    const unsigned short* kst = kb + (size_t)jphys * 32 + s_src * 8;

    union PB { unsigned wo[4]; bf16x8 v8; };

    // prologue: stage tile 0
    *reinterpret_cast<bf16x8*>(ldst0) = *reinterpret_cast<const bf16x8*>(kst);

    for (int jj = 0; jj < 64; ++jj) {
        const int j0 = jj * 64;
        const unsigned short* kbuf = (jj & 1) ? kT[1] : kT[0];
        __syncthreads();                        // staged tile visible to all
        if (jj + 1 < 64) {                      // stage next tile (overlaps compute)
            unsigned short* nd = (jj & 1) ? ldst0 : ldst1;
            *reinterpret_cast<bf16x8*>(nd) =
                *reinterpret_cast<const bf16x8*>(kst + (size_t)(j0 + 64) * 32);
        }

        // ---- QK^T: S^T[j][i] ----
        bf16x8 kA[4];
        #pragma unroll
        for (int jt = 0; jt < 4; ++jt) {
            const int row = jt * 16 + li;
            kA[jt] = *reinterpret_cast<const bf16x8*>(
                reinterpret_cast<const char*>(kbuf) + row * 64 + ((g ^ (row & 3)) << 4));
        }
        f32x4 sT[4][4];
        #pragma unroll
        for (int jt = 0; jt < 4; ++jt)
            #pragma unroll
            for (int it = 0; it < 4; ++it)
                sT[jt][it] = __builtin_amdgcn_mfma_f32_16x16x32_bf16(
                    kA[jt], qf[it], z4, 0, 0, 0);

        // ---- online softmax (all per-lane for i = it*16 + li) ----
        PB pB[2][4];                            // [kt][it]
        #pragma unroll
        for (int it = 0; it < 4; ++it) {
            float mx = sT[0][it][0];
            #pragma unroll
            for (int jt = 0; jt < 4; ++jt)
                #pragma unroll
                for (int r = 0; r < 4; ++r) mx = fmaxf(mx, sT[jt][it][r]);
            mx = fmaxf(mx, __shfl_xor(mx, 16));
            mx = fmaxf(mx, __shfl_xor(mx, 32));
            const float mnew = fmaxf(m_run[it], mx);
            const float f = __expf(m_run[it] - mnew);
            m_run[it] = mnew;
            float p[4][4];
            float sum = 0.f;
            #pragma unroll
            for (int jt = 0; jt < 4; ++jt)
                #pragma unroll
                for (int r = 0; r < 4; ++r) {
                    p[jt][r] = __expf(sT[jt][it][r] - mnew);
                    sum += p[jt][r];
                }
            sum += __shfl_xor(sum, 16);
            sum += __shfl_xor(sum, 32);
            l_run[it] = l_run[it] * f + sum;
            #pragma unroll
            for (int kt = 0; kt < 2; ++kt) {    // j = kt*32 + 8g + 0..7, in-lane
                pB[kt][it].wo[0] = pack2(p[2 * kt][0],     p[2 * kt][1]);
                pB[kt][it].wo[1] = pack2(p[2 * kt][2],     p[2 * kt][3]);
                pB[kt][it].wo[2] = pack2(p[2 * kt + 1][0], p[2 * kt + 1][1]);
                pB[kt][it].wo[3] = pack2(p[2 * kt + 1][2], p[2 * kt + 1][3]);
            }
            #pragma unroll
            for (int ct = 0; ct < 4; ++ct) acc[ct][it] *= f;
        }

        // ---- PV: O^T[c][i] += V[c][j] * P^T[j][i], V straight from global ----
        #pragma unroll
        for (int ct = 0; ct < 4; ++ct) {
            #pragma unroll
            for (int kt = 0; kt < 2; ++kt) {
                const bf16x8 vA = *reinterpret_cast<const bf16x8*>(
                    vb + (size_t)(cw0 + ct * 16 + li) * N_ + j0 + kt * 32 + g * 8);
                #pragma unroll
                for (int it = 0; it < 4; ++it)
                    acc[ct][it] = __builtin_amdgcn_mfma_f32_16x16x32_bf16(
                        vA, pB[kt][it].v8, acc[ct][it], 0, 0, 0);
            }
        }
    }

    // ---- epilogue: out = gamma * (O/l) + x ----
    const float gm = gamma[0];
    float linv[4];
    #pragma unroll
    for (int it = 0; it < 4; ++it) linv[it] = 1.0f / l_run[it];

    const float* xb2 = x + ((size_t)b * C_) * N_;
    float* ob = out + ((size_t)b * C_) * N_;
    #pragma unroll
    for (int ct = 0; ct < 4; ++ct) {
        #pragma unroll
        for (int r = 0; r < 4; ++r) {
            const int c = cw0 + ct * 16 + 4 * g + r;
            #pragma unroll
            for (int it = 0; it < 4; ++it) {
                const int i = i0 + it * 16 + li;
                const size_t off = (size_t)c * N_ + i;
                ob[off] = gm * acc[ct][it][r] * linv[it] + xb2[off];
            }
        }
    }
}

// ---------------------------------------------------------------------------
// Workspace layout (bf16): q [8][4096][32] | k [8][4096][32] | v [8][256][4096]
// = 2 MB + 2 MB + 16 MB = 20 MB in d_ws.
// ---------------------------------------------------------------------------
extern "C" void kernel_launch(void* const* d_in, const int* in_sizes, int n_in,
                              void* d_out, int out_size, void* d_ws, size_t ws_size,
                              hipStream_t stream) {
    const float* x     = (const float*)d_in[0];
    const float* Wq    = (const float*)d_in[1];
    const float* bq    = (const float*)d_in[2];
    const float* Wk    = (const float*)d_in[3];
    const float* bk    = (const float*)d_in[4];
    const float* Wv    = (const float*)d_in[5];
    const float* bv    = (const float*)d_in[6];
    const float* gamma = (const float*)d_in[7];
    float* out = (float*)d_out;

    unsigned short* q = (unsigned short*)d_ws;
    unsigned short* k = q + (size_t)B_ * N_ * 32;
    unsigned short* v = k + (size_t)B_ * N_ * 32;

    dim3 grid(N_ / 64, B_);
    qkv_proj_mfma<<<grid, 256, 0, stream>>>(x, Wq, bq, Wk, bk, Wv, bv, q, k, v);
    attn_mfma<<<grid, 256, 0, stream>>>(q, k, v, x, gamma, out);
}

// Round 3
// 287.928 us; speedup vs baseline: 5.5975x; 1.1003x over previous
//
#include <hip/hip_runtime.h>
#include <hip/hip_bf16.h>
#include <math.h>

// Problem constants: x [8,256,64,64] fp32, N = 4096, C = 256, Cqk = 32.
#define B_   8
#define C_   256
#define N_   4096
// 1/sqrt(32) * log2(e): scores computed directly in log2 space -> exp2f only.
#define QSCALE_L2E 0.2550541451582815f
#define DEFER_THR  11.5f   // defer-max threshold in log2 units (~8 nats)

typedef __attribute__((ext_vector_type(8))) short bf16x8;   // 8 bf16 = 4 VGPRs
typedef __attribute__((ext_vector_type(4))) float f32x4;

__device__ __forceinline__ unsigned short bfu(float f) {
    __hip_bfloat16 h = __float2bfloat16(f);
    return __builtin_bit_cast(unsigned short, h);
}
__device__ __forceinline__ unsigned pack2(float lo, float hi) {
    return ((unsigned)bfu(hi) << 16) | (unsigned)bfu(lo);
}

// ---------------------------------------------------------------------------
// Kernel 0: one-time W -> bf16 prep. wbf layout: Wq[32*256] | Wk | Wv[256*256].
// ---------------------------------------------------------------------------
__global__ __launch_bounds__(256) void w_prep(
    const float* __restrict__ Wq, const float* __restrict__ Wk,
    const float* __restrict__ Wv, unsigned short* __restrict__ wbf)
{
    const int i = blockIdx.x * 256 + threadIdx.x;   // 20480 threads, 4 elems each
    const int off = i * 4;
    float4 f;
    if (off < 32 * C_)            f = *reinterpret_cast<const float4*>(Wq + off);
    else if (off < 64 * C_)       f = *reinterpret_cast<const float4*>(Wk + off - 32 * C_);
    else                          f = *reinterpret_cast<const float4*>(Wv + off - 64 * C_);
    ushort4 u;
    u.x = bfu(f.x); u.y = bfu(f.y); u.z = bfu(f.z); u.w = bfu(f.w);
    *reinterpret_cast<ushort4*>(wbf + off) = u;
}

// ---------------------------------------------------------------------------
// Kernel 1: QKV projection via MFMA. grid (64, 8), block 256 (4 waves).
// LDS: xT [64 n][256 c] bf16, 16B-slot XOR-swizzled. W read as bf16 b128.
// Operand order chosen so D *rows* land on the stored-contiguous dim:
//   v:  D[n][o] = mfma(A=xT, B=Wv^T)  -> rows n (4 consecutive per reg) ... wait
//   (see comments at each epilogue: all stores are short4 = 8B.)
// Outputs: q,k as [b][n][32] bf16 (q pre-scaled by QSCALE_L2E), v as [b][c][n].
// ---------------------------------------------------------------------------
__global__ __launch_bounds__(256, 2) void qkv_proj_mfma(
    const float* __restrict__ x, const unsigned short* __restrict__ wbf,
    const float* __restrict__ bq, const float* __restrict__ bk,
    const float* __restrict__ bv,
    unsigned short* __restrict__ q, unsigned short* __restrict__ k,
    unsigned short* __restrict__ v)
{
    const int b = blockIdx.y, n0 = blockIdx.x * 64;
    const int t = threadIdx.x;
    const int w = t >> 6, l = t & 63;
    const int li = l & 15, g = l >> 4;

    __shared__ unsigned short xT[64 * 256];   // [n][c], swizzled

    // ---- stage x -> xT (transpose + fp32->bf16) ----
    {
        const int n = t & 63;
        const int cq0 = t >> 6;
        const float* xb = x + ((size_t)b * C_) * N_ + n0 + n;
        #pragma unroll 4
        for (int s = 0; s < 16; ++s) {
            const int cq = cq0 + 4 * s;       // c = cq*4 .. +3
            const float f0 = xb[(size_t)(cq * 4 + 0) * N_];
            const float f1 = xb[(size_t)(cq * 4 + 1) * N_];
            const float f2 = xb[(size_t)(cq * 4 + 2) * N_];
            const float f3 = xb[(size_t)(cq * 4 + 3) * N_];
            ushort4 pk;
            pk.x = bfu(f0); pk.y = bfu(f1); pk.z = bfu(f2); pk.w = bfu(f3);
            const int byte = n * 512 + (((cq >> 1) ^ (n & 7)) << 4) + (cq & 1) * 8;
            *reinterpret_cast<ushort4*>(reinterpret_cast<char*>(xT) + byte) = pk;
        }
    }
    __syncthreads();

    const unsigned short* wq_bf = wbf;
    const unsigned short* wk_bf = wbf + 32 * C_;
    const unsigned short* wv_bf = wbf + 64 * C_;

    // wave job for q/k: w=0: q n 0-31; w=1: q n 32-63; w=2/3: same for k
    const unsigned short* wqk_bf = (w < 2) ? wq_bf : wk_bf;
    const float* bqk = (w < 2) ? bq : bk;
    unsigned short* qk_out = (w < 2) ? q : k;
    const float qscl = (w < 2) ? QSCALE_L2E : 1.0f;
    const int mt0 = (w & 1) * 2;
    const int ov0 = w * 64;

    f32x4 accv[4][4];   // [nt][ot]  D[n][o]: rows n = nt*16+4g+r, col o = ov0+ot*16+li
    f32x4 accq[2][2];   // [ot][m2]  D[d][n]: rows d = ot*16+4g+r, col n = (mt0+m2)*16+li
    const f32x4 z4 = {0.f, 0.f, 0.f, 0.f};
    #pragma unroll
    for (int a = 0; a < 4; ++a)
        #pragma unroll
        for (int c2 = 0; c2 < 4; ++c2) accv[a][c2] = z4;
    #pragma unroll
    for (int a = 0; a < 2; ++a)
        #pragma unroll
        for (int c2 = 0; c2 < 2; ++c2) accq[a][c2] = z4;

    #pragma unroll 2
    for (int kk = 0; kk < 8; ++kk) {
        bf16x8 xf[4];
        #pragma unroll
        for (int nt = 0; nt < 4; ++nt) {
            const int row = nt * 16 + li;
            const int byte = row * 512 + (((kk * 4 + g) ^ (row & 7)) << 4);
            xf[nt] = *reinterpret_cast<const bf16x8*>(
                reinterpret_cast<const char*>(xT) + byte);
        }
        // v: A = xf[nt] (X^T rows n), B = Wv^T[c][o] (lane: Wv[o=ov0+ot*16+li][c slice])
        #pragma unroll
        for (int ot = 0; ot < 4; ++ot) {
            const bf16x8 wV = *reinterpret_cast<const bf16x8*>(
                wv_bf + (size_t)(ov0 + ot * 16 + li) * C_ + kk * 32 + g * 8);
            #pragma unroll
            for (int nt = 0; nt < 4; ++nt)
                accv[nt][ot] = __builtin_amdgcn_mfma_f32_16x16x32_bf16(
                    xf[nt], wV, accv[nt][ot], 0, 0, 0);
        }
        // qk: A = Wqk[d][c] (lane: row d = ot*16+li), B = xf (X cols n)
        #pragma unroll
        for (int ot = 0; ot < 2; ++ot) {
            const bf16x8 wA = *reinterpret_cast<const bf16x8*>(
                wqk_bf + (size_t)(ot * 16 + li) * C_ + kk * 32 + g * 8);
            #pragma unroll
            for (int m2 = 0; m2 < 2; ++m2)
                accq[ot][m2] = __builtin_amdgcn_mfma_f32_16x16x32_bf16(
                    wA, xf[mt0 + m2], accq[ot][m2], 0, 0, 0);
        }
    }

    // ---- epilogue v: rows n = nt*16+4g+r (4 consecutive n per reg -> short4) ----
    #pragma unroll
    for (int ot = 0; ot < 4; ++ot) {
        const int o = ov0 + ot * 16 + li;
        const float bias = bv[o];
        #pragma unroll
        for (int nt = 0; nt < 4; ++nt) {
            const int n = nt * 16 + 4 * g;
            ushort4 s4;
            s4.x = bfu(accv[nt][ot][0] + bias);
            s4.y = bfu(accv[nt][ot][1] + bias);
            s4.z = bfu(accv[nt][ot][2] + bias);
            s4.w = bfu(accv[nt][ot][3] + bias);
            *reinterpret_cast<ushort4*>(v + ((size_t)b * C_ + o) * N_ + n0 + n) = s4;
        }
    }
    // ---- epilogue q/k: rows d = ot*16+4g+r (4 consecutive d -> short4 into [n][32]) ----
    #pragma unroll
    for (int ot = 0; ot < 2; ++ot) {
        const int d0 = ot * 16 + 4 * g;
        const float4 b4 = *reinterpret_cast<const float4*>(bqk + d0);
        #pragma unroll
        for (int m2 = 0; m2 < 2; ++m2) {
            const int n = (mt0 + m2) * 16 + li;
            ushort4 s4;
            s4.x = bfu((accq[ot][m2][0] + b4.x) * qscl);
            s4.y = bfu((accq[ot][m2][1] + b4.y) * qscl);
            s4.z = bfu((accq[ot][m2][2] + b4.z) * qscl);
            s4.w = bfu((accq[ot][m2][3] + b4.w) * qscl);
            *reinterpret_cast<ushort4*>(qk_out + ((size_t)b * N_ + n0 + n) * 32 + d0) = s4;
        }
    }
}

// ---------------------------------------------------------------------------
// Kernel 2: flash attention, i-split softmax. grid (64, 8), block 256 (4 waves).
// Wave w computes S^T only for its 16-query slice (4 MFMA, 16 exp/lane),
// packs P in PV-B-frag layout in-register (K rows pre-permuted at staging so
// lane (li,g) holds exactly j = {kt*32+8g .. +7}), publishes to LDS; all
// waves then read all 4 P-frags for their c-slice PV (V direct from global,
// L2-resident). Defer-max (T13): O-rescale skipped unless max grew > THR.
// ---------------------------------------------------------------------------
__global__ __launch_bounds__(256, 2) void attn_mfma(
    const unsigned short* __restrict__ q, const unsigned short* __restrict__ k,
    const unsigned short* __restrict__ v,
    const float* __restrict__ x, const float* __restrict__ gamma,
    float* __restrict__ out)
{
    const int b = blockIdx.y, i0 = blockIdx.x * 64;
    const int t = threadIdx.x;
    const int w = t >> 6, l = t & 63;
    const int li = l & 15, g = l >> 4;
    const int cw0 = w * 64;

    __shared__ unsigned short kT[2][64 * 32];      // double-buffered K tile (8 KB)
    __shared__ unsigned short pS[4][2][64 * 8];    // P frags [it][kt][lane*8] (8 KB)
    __shared__ float f_s[4][16];
    __shared__ float l_s[4][16];
    __shared__ int   flag_s[4];

    const unsigned short* qb = q + (size_t)b * N_ * 32;
    const unsigned short* kb = k + (size_t)b * N_ * 32;
    const unsigned short* vb = v + ((size_t)b * C_) * N_;

    // Q B-frag for OWN 16-query slice only: i = i0 + w*16 + li
    const bf16x8 qf = *reinterpret_cast<const bf16x8*>(
        qb + (size_t)(i0 + w * 16 + li) * 32 + g * 8);

    f32x4 acc[4][4];   // [ct][it] : O^T[c][i]
    const f32x4 z4 = {0.f, 0.f, 0.f, 0.f};
    #pragma unroll
    for (int a = 0; a < 4; ++a)
        #pragma unroll
        for (int c2 = 0; c2 < 4; ++c2) acc[a][c2] = z4;

    float m_run = -3.0e38f, l_run = 0.f;   // own slice only

    // K staging: thread t -> LDS row jr = t>>2, slot sl = t&3.
    // Row permutation: LDS row rho holds physical j so that S^T D-frag
    // (g, r) of frag jt is j = (jt>>1)*32 + (jt&1)*4 + 8g + r.
    const int jr = t >> 2, sl = t & 3;
    const int jt_s = jr >> 4, gg = (jr >> 2) & 3, rr = jr & 3;
    const int jphys = (jt_s >> 1) * 32 + (jt_s & 1) * 4 + gg * 8 + rr;
    const int s_src = sl ^ (jr & 3);               // bank swizzle
    unsigned short* ldst0 = &kT[0][(size_t)t * 8];
    unsigned short* ldst1 = &kT[1][(size_t)t * 8];
    const unsigned short* kst = kb + (size_t)jphys * 32 + s_src * 8;

    union PB { unsigned wo[4]; bf16x8 v8; };

    // prologue: stage tile 0
    *reinterpret_cast<bf16x8*>(ldst0) = *reinterpret_cast<const bf16x8*>(kst);

    for (int jj = 0; jj < 64; ++jj) {
        const int j0 = jj * 64;
        const unsigned short* kbuf = (jj & 1) ? kT[1] : kT[0];
        __syncthreads();                           // A: K(jj) + prev pS reads done
        if (jj + 1 < 64) {
            unsigned short* nd = (jj & 1) ? ldst0 : ldst1;
            *reinterpret_cast<bf16x8*>(nd) =
                *reinterpret_cast<const bf16x8*>(kst + (size_t)(j0 + 64) * 32);
        }

        // ---- QK^T for own slice: S^T[j][i_w] ----
        bf16x8 kA[4];
        #pragma unroll
        for (int jt = 0; jt < 4; ++jt) {
            const int row = jt * 16 + li;
            kA[jt] = *reinterpret_cast<const bf16x8*>(
                reinterpret_cast<const char*>(kbuf) + row * 64 + ((g ^ (row & 3)) << 4));
        }
        f32x4 sT[4];
        #pragma unroll
        for (int jt = 0; jt < 4; ++jt)
            sT[jt] = __builtin_amdgcn_mfma_f32_16x16x32_bf16(kA[jt], qf, z4, 0, 0, 0);

        // ---- softmax (own column i = i0 + w*16 + li), log2 space ----
        float mx = fmaxf(fmaxf(fmaxf(sT[0][0], sT[0][1]), fmaxf(sT[0][2], sT[0][3])),
                         fmaxf(fmaxf(sT[1][0], sT[1][1]), fmaxf(sT[1][2], sT[1][3])));
        mx = fmaxf(mx, fmaxf(fmaxf(fmaxf(sT[2][0], sT[2][1]), fmaxf(sT[2][2], sT[2][3])),
                             fmaxf(fmaxf(sT[3][0], sT[3][1]), fmaxf(sT[3][2], sT[3][3]))));
        mx = fmaxf(mx, __shfl_xor(mx, 16));
        mx = fmaxf(mx, __shfl_xor(mx, 32));
        const bool grow = (mx > m_run + DEFER_THR);
        const int any = __any(grow);
        const float mnew = grow ? mx : m_run;
        const float f = exp2f(m_run - mnew);       // 1.0 when !grow
        m_run = mnew;

        float p[4][4];
        #pragma unroll
        for (int jt = 0; jt < 4; ++jt)
            #pragma unroll
            for (int r = 0; r < 4; ++r) p[jt][r] = exp2f(sT[jt][r] - mnew);
        float sum = ((p[0][0] + p[0][1]) + (p[0][2] + p[0][3]))
                  + ((p[1][0] + p[1][1]) + (p[1][2] + p[1][3]))
                  + ((p[2][0] + p[2][1]) + (p[2][2] + p[2][3]))
                  + ((p[3][0] + p[3][1]) + (p[3][2] + p[3][3]));
        sum += __shfl_xor(sum, 16);
        sum += __shfl_xor(sum, 32);
        l_run = l_run * f + sum;

        // ---- publish P frags (exact PV-B layout), f, flag ----
        PB pb0, pb1;
        pb0.wo[0] = pack2(p[0][0], p[0][1]); pb0.wo[1] = pack2(p[0][2], p[0][3]);
        pb0.wo[2] = pack2(p[1][0], p[1][1]); pb0.wo[3] = pack2(p[1][2], p[1][3]);
        pb1.wo[0] = pack2(p[2][0], p[2][1]); pb1.wo[1] = pack2(p[2][2], p[2][3]);
        pb1.wo[2] = pack2(p[3][0], p[3][1]); pb1.wo[3] = pack2(p[3][2], p[3][3]);
        *reinterpret_cast<bf16x8*>(&pS[w][0][l * 8]) = pb0.v8;
        *reinterpret_cast<bf16x8*>(&pS[w][1][l * 8]) = pb1.v8;
        if (l < 16) f_s[w][l] = f;
        if (l == 0) flag_s[w] = any;
        __syncthreads();                           // B: pS/f/flag ready

        // ---- rescale acc (skipped when no wave-lane grew: defer-max) ----
        #pragma unroll
        for (int it = 0; it < 4; ++it) {
            if (flag_s[it]) {
                const float ff = f_s[it][li];
                #pragma unroll
                for (int ct = 0; ct < 4; ++ct) acc[ct][it] *= ff;
            }
        }

        // ---- PV: O^T[c][i] += V[c][j] * P^T[j][i] ----
        bf16x8 pb[4][2];
        #pragma unroll
        for (int it = 0; it < 4; ++it) {
            pb[it][0] = *reinterpret_cast<const bf16x8*>(&pS[it][0][l * 8]);
            pb[it][1] = *reinterpret_cast<const bf16x8*>(&pS[it][1][l * 8]);
        }
        #pragma unroll
        for (int ct = 0; ct < 4; ++ct) {
            #pragma unroll
            for (int kt = 0; kt < 2; ++kt) {
                const bf16x8 vA = *reinterpret_cast<const bf16x8*>(
                    vb + (size_t)(cw0 + ct * 16 + li) * N_ + j0 + kt * 32 + g * 8);
                #pragma unroll
                for (int it = 0; it < 4; ++it)
                    acc[ct][it] = __builtin_amdgcn_mfma_f32_16x16x32_bf16(
                        vA, pb[it][kt], acc[ct][it], 0, 0, 0);
            }
        }
    }

    // ---- share l across waves, then epilogue: out = gamma * (O/l) + x ----
    if (l < 16) l_s[w][l] = l_run;
    __syncthreads();

    const float gm = gamma[0];
    float linv[4];
    #pragma unroll
    for (int it = 0; it < 4; ++it) linv[it] = 1.0f / l_s[it][li];

    const float* xb2 = x + ((size_t)b * C_) * N_;
    float* ob = out + ((size_t)b * C_) * N_;
    #pragma unroll
    for (int ct = 0; ct < 4; ++ct) {
        #pragma unroll
        for (int r = 0; r < 4; ++r) {
            const int c = cw0 + ct * 16 + 4 * g + r;
            #pragma unroll
            for (int it = 0; it < 4; ++it) {
                const int i = i0 + it * 16 + li;
                const size_t off = (size_t)c * N_ + i;
                ob[off] = gm * acc[ct][it][r] * linv[it] + xb2[off];
            }
        }
    }
}

// ---------------------------------------------------------------------------
// Workspace: q [8][4096][32] | k | v [8][256][4096] bf16 | wbf [320*256] bf16
// = 2 + 2 + 16 + 0.16 MB = ~20.2 MB in d_ws.
// ---------------------------------------------------------------------------
extern "C" void kernel_launch(void* const* d_in, const int* in_sizes, int n_in,
                              void* d_out, int out_size, void* d_ws, size_t ws_size,
                              hipStream_t stream) {
    const float* x     = (const float*)d_in[0];
    const float* Wq    = (const float*)d_in[1];
    const float* bq    = (const float*)d_in[2];
    const float* Wk    = (const float*)d_in[3];
    const float* bk    = (const float*)d_in[4];
    const float* Wv    = (const float*)d_in[5];
    const float* bv    = (const float*)d_in[6];
    const float* gamma = (const float*)d_in[7];
    float* out = (float*)d_out;

    unsigned short* q   = (unsigned short*)d_ws;
    unsigned short* k   = q + (size_t)B_ * N_ * 32;
    unsigned short* v   = k + (size_t)B_ * N_ * 32;
    unsigned short* wbf = v + (size_t)B_ * C_ * N_;

    dim3 grid(N_ / 64, B_);
    w_prep<<<80, 256, 0, stream>>>(Wq, Wk, Wv, wbf);
    qkv_proj_mfma<<<grid, 256, 0, stream>>>(x, wbf, bq, bk, bv, q, k, v);
    attn_mfma<<<grid, 256, 0, stream>>>(q, k, v, x, gamma, out);
}

// Round 4
// 223.569 us; speedup vs baseline: 7.2089x; 1.2879x over previous
//
#include <hip/hip_runtime.h>
#include <hip/hip_bf16.h>
#include <math.h>

// Problem constants: x [8,256,64,64] fp32, N = 4096, C = 256, Cqk = 32.
#define B_   8
#define C_   256
#define N_   4096
// 1/sqrt(32) * log2(e): scores computed directly in log2 space -> exp2f only.
#define QSCALE_L2E 0.2550541451582815f
#define DEFER_THR  11.5f   // defer-max threshold in log2 units (~8 nats)

typedef __attribute__((ext_vector_type(8))) short bf16x8;   // 8 bf16 = 4 VGPRs
typedef __attribute__((ext_vector_type(4))) float f32x4;

__device__ __forceinline__ unsigned short bfu(float f) {
    __hip_bfloat16 h = __float2bfloat16(f);
    return __builtin_bit_cast(unsigned short, h);
}
__device__ __forceinline__ unsigned pack2(float lo, float hi) {
    return ((unsigned)bfu(hi) << 16) | (unsigned)bfu(lo);
}

// ---------------------------------------------------------------------------
// Kernel 0: one-time W -> bf16 prep. wbf layout: Wq[32*256] | Wk | Wv[256*256].
// ---------------------------------------------------------------------------
__global__ __launch_bounds__(256) void w_prep(
    const float* __restrict__ Wq, const float* __restrict__ Wk,
    const float* __restrict__ Wv, unsigned short* __restrict__ wbf)
{
    const int i = blockIdx.x * 256 + threadIdx.x;
    const int off = i * 4;
    float4 f;
    if (off < 32 * C_)            f = *reinterpret_cast<const float4*>(Wq + off);
    else if (off < 64 * C_)       f = *reinterpret_cast<const float4*>(Wk + off - 32 * C_);
    else                          f = *reinterpret_cast<const float4*>(Wv + off - 64 * C_);
    ushort4 u;
    u.x = bfu(f.x); u.y = bfu(f.y); u.z = bfu(f.z); u.w = bfu(f.w);
    *reinterpret_cast<ushort4*>(wbf + off) = u;
}

// ---------------------------------------------------------------------------
// Kernel 1: QKV projection via MFMA (unchanged from round 3).
// Outputs: q,k as [b][n][32] bf16 (q pre-scaled by QSCALE_L2E), v as [b][c][n].
// ---------------------------------------------------------------------------
__global__ __launch_bounds__(256, 2) void qkv_proj_mfma(
    const float* __restrict__ x, const unsigned short* __restrict__ wbf,
    const float* __restrict__ bq, const float* __restrict__ bk,
    const float* __restrict__ bv,
    unsigned short* __restrict__ q, unsigned short* __restrict__ k,
    unsigned short* __restrict__ v)
{
    const int b = blockIdx.y, n0 = blockIdx.x * 64;
    const int t = threadIdx.x;
    const int w = t >> 6, l = t & 63;
    const int li = l & 15, g = l >> 4;

    __shared__ unsigned short xT[64 * 256];   // [n][c], swizzled

    {
        const int n = t & 63;
        const int cq0 = t >> 6;
        const float* xb = x + ((size_t)b * C_) * N_ + n0 + n;
        #pragma unroll 4
        for (int s = 0; s < 16; ++s) {
            const int cq = cq0 + 4 * s;
            const float f0 = xb[(size_t)(cq * 4 + 0) * N_];
            const float f1 = xb[(size_t)(cq * 4 + 1) * N_];
            const float f2 = xb[(size_t)(cq * 4 + 2) * N_];
            const float f3 = xb[(size_t)(cq * 4 + 3) * N_];
            ushort4 pk;
            pk.x = bfu(f0); pk.y = bfu(f1); pk.z = bfu(f2); pk.w = bfu(f3);
            const int byte = n * 512 + (((cq >> 1) ^ (n & 7)) << 4) + (cq & 1) * 8;
            *reinterpret_cast<ushort4*>(reinterpret_cast<char*>(xT) + byte) = pk;
        }
    }
    __syncthreads();

    const unsigned short* wq_bf = wbf;
    const unsigned short* wk_bf = wbf + 32 * C_;
    const unsigned short* wv_bf = wbf + 64 * C_;

    const unsigned short* wqk_bf = (w < 2) ? wq_bf : wk_bf;
    const float* bqk = (w < 2) ? bq : bk;
    unsigned short* qk_out = (w < 2) ? q : k;
    const float qscl = (w < 2) ? QSCALE_L2E : 1.0f;
    const int mt0 = (w & 1) * 2;
    const int ov0 = w * 64;

    f32x4 accv[4][4];
    f32x4 accq[2][2];
    const f32x4 z4 = {0.f, 0.f, 0.f, 0.f};
    #pragma unroll
    for (int a = 0; a < 4; ++a)
        #pragma unroll
        for (int c2 = 0; c2 < 4; ++c2) accv[a][c2] = z4;
    #pragma unroll
    for (int a = 0; a < 2; ++a)
        #pragma unroll
        for (int c2 = 0; c2 < 2; ++c2) accq[a][c2] = z4;

    #pragma unroll 2
    for (int kk = 0; kk < 8; ++kk) {
        bf16x8 xf[4];
        #pragma unroll
        for (int nt = 0; nt < 4; ++nt) {
            const int row = nt * 16 + li;
            const int byte = row * 512 + (((kk * 4 + g) ^ (row & 7)) << 4);
            xf[nt] = *reinterpret_cast<const bf16x8*>(
                reinterpret_cast<const char*>(xT) + byte);
        }
        #pragma unroll
        for (int ot = 0; ot < 4; ++ot) {
            const bf16x8 wV = *reinterpret_cast<const bf16x8*>(
                wv_bf + (size_t)(ov0 + ot * 16 + li) * C_ + kk * 32 + g * 8);
            #pragma unroll
            for (int nt = 0; nt < 4; ++nt)
                accv[nt][ot] = __builtin_amdgcn_mfma_f32_16x16x32_bf16(
                    xf[nt], wV, accv[nt][ot], 0, 0, 0);
        }
        #pragma unroll
        for (int ot = 0; ot < 2; ++ot) {
            const bf16x8 wA = *reinterpret_cast<const bf16x8*>(
                wqk_bf + (size_t)(ot * 16 + li) * C_ + kk * 32 + g * 8);
            #pragma unroll
            for (int m2 = 0; m2 < 2; ++m2)
                accq[ot][m2] = __builtin_amdgcn_mfma_f32_16x16x32_bf16(
                    wA, xf[mt0 + m2], accq[ot][m2], 0, 0, 0);
        }
    }

    #pragma unroll
    for (int ot = 0; ot < 4; ++ot) {
        const int o = ov0 + ot * 16 + li;
        const float bias = bv[o];
        #pragma unroll
        for (int nt = 0; nt < 4; ++nt) {
            const int n = nt * 16 + 4 * g;
            ushort4 s4;
            s4.x = bfu(accv[nt][ot][0] + bias);
            s4.y = bfu(accv[nt][ot][1] + bias);
            s4.z = bfu(accv[nt][ot][2] + bias);
            s4.w = bfu(accv[nt][ot][3] + bias);
            *reinterpret_cast<ushort4*>(v + ((size_t)b * C_ + o) * N_ + n0 + n) = s4;
        }
    }
    #pragma unroll
    for (int ot = 0; ot < 2; ++ot) {
        const int d0 = ot * 16 + 4 * g;
        const float4 b4 = *reinterpret_cast<const float4*>(bqk + d0);
        #pragma unroll
        for (int m2 = 0; m2 < 2; ++m2) {
            const int n = (mt0 + m2) * 16 + li;
            ushort4 s4;
            s4.x = bfu((accq[ot][m2][0] + b4.x) * qscl);
            s4.y = bfu((accq[ot][m2][1] + b4.y) * qscl);
            s4.z = bfu((accq[ot][m2][2] + b4.z) * qscl);
            s4.w = bfu((accq[ot][m2][3] + b4.w) * qscl);
            *reinterpret_cast<ushort4*>(qk_out + ((size_t)b * N_ + n0 + n) * 32 + d0) = s4;
        }
    }
}

// ---------------------------------------------------------------------------
// Kernel 2: flash attention, KVBLK=128, batch->XCD swizzle, V prefetch (T14).
// grid 512 (1-D): b = id & 7 (XCD-local batch), i0 = (id>>3)*64. 4 waves.
// Per iter (128 j): barrier A -> issue 16 V b128 loads + K(jj+1) prefetch
// -> QK (8 MFMA) -> softmax (32 exp2/lane, defer-max) -> pS publish ->
// barrier B -> rescale + PV (64 MFMA, V regs already resident).
// ---------------------------------------------------------------------------
__global__ __launch_bounds__(256, 2) void attn_mfma(
    const unsigned short* __restrict__ q, const unsigned short* __restrict__ k,
    const unsigned short* __restrict__ v,
    const float* __restrict__ x, const float* __restrict__ gamma,
    float* __restrict__ out)
{
    const int id = blockIdx.x;
    const int b = id & 7;                 // batch == XCD (linear id % 8)
    const int i0 = (id >> 3) * 64;
    const int t = threadIdx.x;
    const int w = t >> 6, l = t & 63;
    const int li = l & 15, g = l >> 4;
    const int cw0 = w * 64;

    __shared__ unsigned short kT[2][128 * 32];     // double-buffered K tile (16 KB)
    __shared__ unsigned short pS[4][4][64 * 8];    // P frags [it][kt][lane*8] (16 KB)
    __shared__ float f_s[4][16];
    __shared__ float l_s[4][16];
    __shared__ int   flag_s[4];

    const unsigned short* qb = q + (size_t)b * N_ * 32;
    const unsigned short* kb = k + (size_t)b * N_ * 32;
    const unsigned short* vb = v + ((size_t)b * C_) * N_;

    // Q B-frag for OWN 16-query slice: i = i0 + w*16 + li
    const bf16x8 qf = *reinterpret_cast<const bf16x8*>(
        qb + (size_t)(i0 + w * 16 + li) * 32 + g * 8);

    f32x4 acc[4][4];   // [ct][it] : O^T[c][i]
    const f32x4 z4 = {0.f, 0.f, 0.f, 0.f};
    #pragma unroll
    for (int a = 0; a < 4; ++a)
        #pragma unroll
        for (int c2 = 0; c2 < 4; ++c2) acc[a][c2] = z4;

    float m_run = -3.0e38f, l_run = 0.f;

    // K staging: thread t -> LDS shorts [h*2048 + t*8 .. +7] per half h.
    // Row permutation (per 64-row half): LDS row rho holds physical j so that
    // S^T D-frag (g, r) of frag jt is j = (jt>>1)*32 + (jt&1)*4 + 8g + r.
    const int jr = t >> 2, sl = t & 3;
    const int jt_s = jr >> 4, gg = (jr >> 2) & 3, rr = jr & 3;
    const int jperm = (jt_s >> 1) * 32 + (jt_s & 1) * 4 + gg * 8 + rr;
    const int s_src = sl ^ (jr & 3);               // bank swizzle
    const unsigned short* kst = kb + (size_t)jperm * 32 + s_src * 8;

    union PB { unsigned wo[4]; bf16x8 v8; };

    // prologue: stage tile 0 (both halves) into kT[0]
    {
        const bf16x8 a0 = *reinterpret_cast<const bf16x8*>(kst);
        const bf16x8 a1 = *reinterpret_cast<const bf16x8*>(kst + 64 * 32);
        *reinterpret_cast<bf16x8*>(&kT[0][t * 8]) = a0;
        *reinterpret_cast<bf16x8*>(&kT[0][2048 + t * 8]) = a1;
    }

    for (int jj = 0; jj < 32; ++jj) {
        const int j0 = jj * 128;
        const char* kbuf = reinterpret_cast<const char*>(&kT[jj & 1][0]);
        __syncthreads();                           // A: kT[cur] staged, pS free

        // ---- issue K(jj+1) prefetch loads (oldest in queue) ----
        bf16x8 knx0, knx1;
        const bool have = (jj + 1 < 32);
        if (have) {
            knx0 = *reinterpret_cast<const bf16x8*>(kst + (size_t)(j0 + 128) * 32);
            knx1 = *reinterpret_cast<const bf16x8*>(kst + (size_t)(j0 + 192) * 32);
        }
        // ---- issue ALL V loads for this tile (consumed after barrier B) ----
        bf16x8 vA[4][4];   // [ct][kt]
        #pragma unroll
        for (int ct = 0; ct < 4; ++ct)
            #pragma unroll
            for (int kt = 0; kt < 4; ++kt)
                vA[ct][kt] = *reinterpret_cast<const bf16x8*>(
                    vb + (size_t)(cw0 + ct * 16 + li) * N_ + j0 + kt * 32 + g * 8);

        // ---- QK^T for own slice: S^T frags over 128 j ----
        f32x4 sT[8];
        #pragma unroll
        for (int h = 0; h < 2; ++h) {
            #pragma unroll
            for (int jt = 0; jt < 4; ++jt) {
                const int row = jt * 16 + li;
                const bf16x8 kA = *reinterpret_cast<const bf16x8*>(
                    kbuf + h * 4096 + row * 64 + ((g ^ (row & 3)) << 4));
                sT[h * 4 + jt] = __builtin_amdgcn_mfma_f32_16x16x32_bf16(
                    kA, qf, z4, 0, 0, 0);
            }
        }

        // ---- softmax (own column i), log2 space, defer-max ----
        float mx = sT[0][0];
        #pragma unroll
        for (int f8 = 0; f8 < 8; ++f8)
            #pragma unroll
            for (int r = 0; r < 4; ++r) mx = fmaxf(mx, sT[f8][r]);
        mx = fmaxf(mx, __shfl_xor(mx, 16));
        mx = fmaxf(mx, __shfl_xor(mx, 32));
        const bool grow = (mx > m_run + DEFER_THR);
        const int any = __any(grow);
        const float mnew = grow ? mx : m_run;
        const float f = grow ? exp2f(m_run - mnew) : 1.0f;
        m_run = mnew;

        float p[8][4];
        float sum = 0.f;
        #pragma unroll
        for (int f8 = 0; f8 < 8; ++f8)
            #pragma unroll
            for (int r = 0; r < 4; ++r) {
                p[f8][r] = exp2f(sT[f8][r] - mnew);
                sum += p[f8][r];
            }
        sum += __shfl_xor(sum, 16);
        sum += __shfl_xor(sum, 32);
        l_run = l_run * f + sum;

        // ---- publish P frags (PV-B layout: kt from frag pair 2kt,2kt+1) ----
        #pragma unroll
        for (int kt = 0; kt < 4; ++kt) {
            PB pk;
            pk.wo[0] = pack2(p[2 * kt][0],     p[2 * kt][1]);
            pk.wo[1] = pack2(p[2 * kt][2],     p[2 * kt][3]);
            pk.wo[2] = pack2(p[2 * kt + 1][0], p[2 * kt + 1][1]);
            pk.wo[3] = pack2(p[2 * kt + 1][2], p[2 * kt + 1][3]);
            *reinterpret_cast<bf16x8*>(&pS[w][kt][l * 8]) = pk.v8;
        }
        if (l < 16) f_s[w][l] = f;
        if (l == 0) flag_s[w] = any;

        // ---- write K(jj+1) into other buffer (load latency already hidden) ----
        if (have) {
            unsigned short* knd = &kT[(jj + 1) & 1][0];
            *reinterpret_cast<bf16x8*>(&knd[t * 8]) = knx0;
            *reinterpret_cast<bf16x8*>(&knd[2048 + t * 8]) = knx1;
        }
        __syncthreads();                           // B: pS/f/flag ready

        // ---- rescale acc (defer-max: usually skipped) ----
        #pragma unroll
        for (int it = 0; it < 4; ++it) {
            if (flag_s[it]) {
                const float ff = f_s[it][li];
                #pragma unroll
                for (int ct = 0; ct < 4; ++ct) acc[ct][it] *= ff;
            }
        }

        // ---- PV: O^T[c][i] += V[c][j] * P^T[j][i], V already in registers ----
        #pragma unroll
        for (int kt = 0; kt < 4; ++kt) {
            bf16x8 pb0 = *reinterpret_cast<const bf16x8*>(&pS[0][kt][l * 8]);
            bf16x8 pb1 = *reinterpret_cast<const bf16x8*>(&pS[1][kt][l * 8]);
            bf16x8 pb2 = *reinterpret_cast<const bf16x8*>(&pS[2][kt][l * 8]);
            bf16x8 pb3 = *reinterpret_cast<const bf16x8*>(&pS[3][kt][l * 8]);
            #pragma unroll
            for (int ct = 0; ct < 4; ++ct) {
                acc[ct][0] = __builtin_amdgcn_mfma_f32_16x16x32_bf16(vA[ct][kt], pb0, acc[ct][0], 0, 0, 0);
                acc[ct][1] = __builtin_amdgcn_mfma_f32_16x16x32_bf16(vA[ct][kt], pb1, acc[ct][1], 0, 0, 0);
                acc[ct][2] = __builtin_amdgcn_mfma_f32_16x16x32_bf16(vA[ct][kt], pb2, acc[ct][2], 0, 0, 0);
                acc[ct][3] = __builtin_amdgcn_mfma_f32_16x16x32_bf16(vA[ct][kt], pb3, acc[ct][3], 0, 0, 0);
            }
        }
    }

    // ---- share l across waves, then epilogue: out = gamma * (O/l) + x ----
    if (l < 16) l_s[w][l] = l_run;
    __syncthreads();

    const float gm = gamma[0];
    float linv[4];
    #pragma unroll
    for (int it = 0; it < 4; ++it) linv[it] = 1.0f / l_s[it][li];

    const float* xb2 = x + ((size_t)b * C_) * N_;
    float* ob = out + ((size_t)b * C_) * N_;
    #pragma unroll
    for (int ct = 0; ct < 4; ++ct) {
        #pragma unroll
        for (int r = 0; r < 4; ++r) {
            const int c = cw0 + ct * 16 + 4 * g + r;
            #pragma unroll
            for (int it = 0; it < 4; ++it) {
                const int i = i0 + it * 16 + li;
                const size_t off = (size_t)c * N_ + i;
                ob[off] = gm * acc[ct][it][r] * linv[it] + xb2[off];
            }
        }
    }
}

// ---------------------------------------------------------------------------
// Workspace: q [8][4096][32] | k | v [8][256][4096] bf16 | wbf [320*256] bf16
// = 2 + 2 + 16 + 0.16 MB = ~20.2 MB in d_ws.
// ---------------------------------------------------------------------------
extern "C" void kernel_launch(void* const* d_in, const int* in_sizes, int n_in,
                              void* d_out, int out_size, void* d_ws, size_t ws_size,
                              hipStream_t stream) {
    const float* x     = (const float*)d_in[0];
    const float* Wq    = (const float*)d_in[1];
    const float* bq    = (const float*)d_in[2];
    const float* Wk    = (const float*)d_in[3];
    const float* bk    = (const float*)d_in[4];
    const float* Wv    = (const float*)d_in[5];
    const float* bv    = (const float*)d_in[6];
    const float* gamma = (const float*)d_in[7];
    float* out = (float*)d_out;

    unsigned short* q   = (unsigned short*)d_ws;
    unsigned short* k   = q + (size_t)B_ * N_ * 32;
    unsigned short* v   = k + (size_t)B_ * N_ * 32;
    unsigned short* wbf = v + (size_t)B_ * C_ * N_;

    dim3 grid(N_ / 64, B_);
    w_prep<<<80, 256, 0, stream>>>(Wq, Wk, Wv, wbf);
    qkv_proj_mfma<<<grid, 256, 0, stream>>>(x, wbf, bq, bk, bv, q, k, v);
    attn_mfma<<<512, 256, 0, stream>>>(q, k, v, x, gamma, out);
}

// Round 5
// 188.132 us; speedup vs baseline: 8.5667x; 1.1884x over previous
//
#include <hip/hip_runtime.h>
#include <hip/hip_bf16.h>
#include <math.h>

// Problem constants: x [8,256,64,64] fp32, N = 4096, C = 256, Cqk = 32.
#define B_   8
#define C_   256
#define N_   4096
// 1/sqrt(32) * log2(e): scores computed directly in log2 space -> exp2f only.
#define QSCALE_L2E 0.2550541451582815f
#define DEFER_THR  11.5f   // defer-max threshold in log2 units (~8 nats)

typedef __attribute__((ext_vector_type(8))) short bf16x8;   // 8 bf16 = 4 VGPRs
typedef __attribute__((ext_vector_type(4))) float f32x4;

__device__ __forceinline__ unsigned short bfu(float f) {
    __hip_bfloat16 h = __float2bfloat16(f);
    return __builtin_bit_cast(unsigned short, h);
}
__device__ __forceinline__ unsigned pack2(float lo, float hi) {
    return ((unsigned)bfu(hi) << 16) | (unsigned)bfu(lo);
}

// ---------------------------------------------------------------------------
// Kernel 0: one-time W -> bf16 prep. wbf layout: Wq[32*256] | Wk | Wv[256*256].
// ---------------------------------------------------------------------------
__global__ __launch_bounds__(256) void w_prep(
    const float* __restrict__ Wq, const float* __restrict__ Wk,
    const float* __restrict__ Wv, unsigned short* __restrict__ wbf)
{
    const int i = blockIdx.x * 256 + threadIdx.x;
    const int off = i * 4;
    float4 f;
    if (off < 32 * C_)            f = *reinterpret_cast<const float4*>(Wq + off);
    else if (off < 64 * C_)       f = *reinterpret_cast<const float4*>(Wk + off - 32 * C_);
    else                          f = *reinterpret_cast<const float4*>(Wv + off - 64 * C_);
    ushort4 u;
    u.x = bfu(f.x); u.y = bfu(f.y); u.z = bfu(f.z); u.w = bfu(f.w);
    *reinterpret_cast<ushort4*>(wbf + off) = u;
}

// ---------------------------------------------------------------------------
// Kernel 1: QKV projection via MFMA. grid (64, 8), block 256 (4 waves).
// Main loop unchanged (round 3). NEW epilogue: acc -> LDS transpose (swizzled
// 8B slots) -> fully coalesced dwordx4 global stores (old path was 8B
// scattered stores; v=16MB at 8B granularity was the proj bottleneck).
// Outputs: q,k as [b][n][32] bf16 (q pre-scaled by QSCALE_L2E), v as [b][c][n].
// ---------------------------------------------------------------------------
__global__ __launch_bounds__(256, 2) void qkv_proj_mfma(
    const float* __restrict__ x, const unsigned short* __restrict__ wbf,
    const float* __restrict__ bq, const float* __restrict__ bk,
    const float* __restrict__ bv,
    unsigned short* __restrict__ q, unsigned short* __restrict__ k,
    unsigned short* __restrict__ v)
{
    const int b = blockIdx.y, n0 = blockIdx.x * 64;
    const int t = threadIdx.x;
    const int w = t >> 6, l = t & 63;
    const int li = l & 15, g = l >> 4;

    __shared__ unsigned short xT[64 * 256];     // 32 KB: [n][c] swizzled; reused as vS[256 o][64 n]
    __shared__ unsigned short qkS[2 * 64 * 32]; // 8 KB: [qk][n][d], swizzled 8B slots

    // ---- stage x -> xT (transpose + fp32->bf16) ----
    {
        const int n = t & 63;
        const int cq0 = t >> 6;
        const float* xb = x + ((size_t)b * C_) * N_ + n0 + n;
        #pragma unroll 4
        for (int s = 0; s < 16; ++s) {
            const int cq = cq0 + 4 * s;
            const float f0 = xb[(size_t)(cq * 4 + 0) * N_];
            const float f1 = xb[(size_t)(cq * 4 + 1) * N_];
            const float f2 = xb[(size_t)(cq * 4 + 2) * N_];
            const float f3 = xb[(size_t)(cq * 4 + 3) * N_];
            ushort4 pk;
            pk.x = bfu(f0); pk.y = bfu(f1); pk.z = bfu(f2); pk.w = bfu(f3);
            const int byte = n * 512 + (((cq >> 1) ^ (n & 7)) << 4) + (cq & 1) * 8;
            *reinterpret_cast<ushort4*>(reinterpret_cast<char*>(xT) + byte) = pk;
        }
    }
    __syncthreads();

    const unsigned short* wq_bf = wbf;
    const unsigned short* wk_bf = wbf + 32 * C_;
    const unsigned short* wv_bf = wbf + 64 * C_;

    const unsigned short* wqk_bf = (w < 2) ? wq_bf : wk_bf;
    const float* bqk = (w < 2) ? bq : bk;
    const float qscl = (w < 2) ? QSCALE_L2E : 1.0f;
    const int mt0 = (w & 1) * 2;
    const int ov0 = w * 64;

    f32x4 accv[4][4];   // [nt][ot]  D[n][o]: n = nt*16+4g+r, o = ov0+ot*16+li
    f32x4 accq[2][2];   // [ot][m2]  D[d][n]: d = ot*16+4g+r, n = (mt0+m2)*16+li
    const f32x4 z4 = {0.f, 0.f, 0.f, 0.f};
    #pragma unroll
    for (int a = 0; a < 4; ++a)
        #pragma unroll
        for (int c2 = 0; c2 < 4; ++c2) accv[a][c2] = z4;
    #pragma unroll
    for (int a = 0; a < 2; ++a)
        #pragma unroll
        for (int c2 = 0; c2 < 2; ++c2) accq[a][c2] = z4;

    #pragma unroll 2
    for (int kk = 0; kk < 8; ++kk) {
        bf16x8 xf[4];
        #pragma unroll
        for (int nt = 0; nt < 4; ++nt) {
            const int row = nt * 16 + li;
            const int byte = row * 512 + (((kk * 4 + g) ^ (row & 7)) << 4);
            xf[nt] = *reinterpret_cast<const bf16x8*>(
                reinterpret_cast<const char*>(xT) + byte);
        }
        #pragma unroll
        for (int ot = 0; ot < 4; ++ot) {
            const bf16x8 wV = *reinterpret_cast<const bf16x8*>(
                wv_bf + (size_t)(ov0 + ot * 16 + li) * C_ + kk * 32 + g * 8);
            #pragma unroll
            for (int nt = 0; nt < 4; ++nt)
                accv[nt][ot] = __builtin_amdgcn_mfma_f32_16x16x32_bf16(
                    xf[nt], wV, accv[nt][ot], 0, 0, 0);
        }
        #pragma unroll
        for (int ot = 0; ot < 2; ++ot) {
            const bf16x8 wA = *reinterpret_cast<const bf16x8*>(
                wqk_bf + (size_t)(ot * 16 + li) * C_ + kk * 32 + g * 8);
            #pragma unroll
            for (int m2 = 0; m2 < 2; ++m2)
                accq[ot][m2] = __builtin_amdgcn_mfma_f32_16x16x32_bf16(
                    wA, xf[mt0 + m2], accq[ot][m2], 0, 0, 0);
        }
    }

    __syncthreads();   // all xT reads done: safe to reuse xT as vS

    // ---- q/k accs -> qkS[qk][n][d] (8B slots, slot' = slot ^ (n&7)) ----
    {
        const int qk = (w < 2) ? 0 : 1;
        #pragma unroll
        for (int ot = 0; ot < 2; ++ot) {
            const int d0 = ot * 16 + 4 * g;
            const float4 b4 = *reinterpret_cast<const float4*>(bqk + d0);
            const int slot = ot * 4 + g;            // d0/4
            #pragma unroll
            for (int m2 = 0; m2 < 2; ++m2) {
                const int n = (mt0 + m2) * 16 + li;
                ushort4 s4;
                s4.x = bfu((accq[ot][m2][0] + b4.x) * qscl);
                s4.y = bfu((accq[ot][m2][1] + b4.y) * qscl);
                s4.z = bfu((accq[ot][m2][2] + b4.z) * qscl);
                s4.w = bfu((accq[ot][m2][3] + b4.w) * qscl);
                const int byte = qk * 4096 + n * 64 + ((slot ^ (n & 7)) << 3);
                *reinterpret_cast<ushort4*>(reinterpret_cast<char*>(qkS) + byte) = s4;
            }
        }
    }
    // ---- v accs -> vS[o][n] (8B slots, 16/row, slot' = slot ^ (o&7)) ----
    {
        #pragma unroll
        for (int ot = 0; ot < 4; ++ot) {
            const int o = ov0 + ot * 16 + li;
            const float bias = bv[o];
            #pragma unroll
            for (int nt = 0; nt < 4; ++nt) {
                ushort4 s4;
                s4.x = bfu(accv[nt][ot][0] + bias);
                s4.y = bfu(accv[nt][ot][1] + bias);
                s4.z = bfu(accv[nt][ot][2] + bias);
                s4.w = bfu(accv[nt][ot][3] + bias);
                const int slot = nt * 4 + g;        // (nt*16+4g)/4
                const int byte = o * 128 + ((slot ^ (o & 7)) << 3);
                *reinterpret_cast<ushort4*>(reinterpret_cast<char*>(xT) + byte) = s4;
            }
        }
    }
    __syncthreads();

    // ---- coalesced q/k stores: each tile is 4 KB CONTIGUOUS in global ----
    {
        const char* qks = reinterpret_cast<const char*>(qkS);
        #pragma unroll
        for (int qk = 0; qk < 2; ++qk) {
            const int n = t >> 2, s2 = (t & 3) * 2;
            const int byteA = qk * 4096 + n * 64 + (((s2    ) ^ (n & 7)) << 3);
            const int byteB = qk * 4096 + n * 64 + (((s2 + 1) ^ (n & 7)) << 3);
            const uint2 lo = *reinterpret_cast<const uint2*>(qks + byteA);
            const uint2 hi = *reinterpret_cast<const uint2*>(qks + byteB);
            uint4 val = make_uint4(lo.x, lo.y, hi.x, hi.y);
            unsigned short* dst = (qk == 0) ? q : k;
            *reinterpret_cast<uint4*>(dst + ((size_t)b * N_ + n0) * 32 + t * 8) = val;
        }
    }
    // ---- coalesced v stores: 8 passes of 32 rows x 128 B ----
    {
        const char* vs = reinterpret_cast<const char*>(xT);
        #pragma unroll
        for (int p2 = 0; p2 < 8; ++p2) {
            const int o = p2 * 32 + (t >> 3);
            const int s2 = (t & 7) * 2;
            const int byteA = o * 128 + (((s2    ) ^ (o & 7)) << 3);
            const int byteB = o * 128 + (((s2 + 1) ^ (o & 7)) << 3);
            const uint2 lo = *reinterpret_cast<const uint2*>(vs + byteA);
            const uint2 hi = *reinterpret_cast<const uint2*>(vs + byteB);
            uint4 val = make_uint4(lo.x, lo.y, hi.x, hi.y);
            *reinterpret_cast<uint4*>(v + ((size_t)b * C_ + o) * N_ + n0 + (t & 7) * 8) = val;
        }
    }
}

// ---------------------------------------------------------------------------
// Kernel 2: flash attention. grid 512 1-D (b = id&7 -> XCD-local), 4 waves.
// ONE barrier per 128-j iteration: pS/f/flag double-buffered, PV skewed one
// tile. K(jj+1) + V(jj-1) issued via inline-asm global_load_dwordx4 right
// after the barrier (compiler cannot sink them); manual vmcnt(16) before the
// K LDS write, vmcnt(0) before PV, each followed by sched_barrier(0).
// Softmax: per-lane partial l (cross-lane reduce ONCE at end); cross-lane max
// only on the rare defer-max growth path.
// ---------------------------------------------------------------------------
__global__ __launch_bounds__(256, 2) void attn_mfma(
    const unsigned short* __restrict__ q, const unsigned short* __restrict__ k,
    const unsigned short* __restrict__ v,
    const float* __restrict__ x, const float* __restrict__ gamma,
    float* __restrict__ out)
{
    const int id = blockIdx.x;
    const int b = id & 7;                 // batch == XCD
    const int i0 = (id >> 3) * 64;
    const int t = threadIdx.x;
    const int w = t >> 6, l = t & 63;
    const int li = l & 15, g = l >> 4;
    const int cw0 = w * 64;

    __shared__ unsigned short kT[2][128 * 32];      // 16 KB double-buffered K
    __shared__ unsigned short pS[2][4][4][64 * 8];  // 32 KB double-buffered P
    __shared__ float f_s[2][4][16];
    __shared__ int   flag_s[2][4];
    __shared__ float l_s[4][16];

    const unsigned short* qb = q + (size_t)b * N_ * 32;
    const unsigned short* kb = k + (size_t)b * N_ * 32;
    const unsigned short* vb = v + ((size_t)b * C_) * N_;

    // Q B-frag for OWN 16-query slice: i = i0 + w*16 + li
    const bf16x8 qf = *reinterpret_cast<const bf16x8*>(
        qb + (size_t)(i0 + w * 16 + li) * 32 + g * 8);

    f32x4 acc[4][4];   // [ct][it] : O^T[c][i]
    const f32x4 z4 = {0.f, 0.f, 0.f, 0.f};
    #pragma unroll
    for (int a = 0; a < 4; ++a)
        #pragma unroll
        for (int c2 = 0; c2 < 4; ++c2) acc[a][c2] = z4;

    float m_run = -3.0e38f;
    float l_part = 0.f;   // per-lane partial sum (own j subset)

    // K staging constants (row-permuted so S^T D-frag rows are PV-B-frag j's)
    const int jr = t >> 2, sl = t & 3;
    const int jt_s = jr >> 4, gg = (jr >> 2) & 3, rr = jr & 3;
    const int jperm = (jt_s >> 1) * 32 + (jt_s & 1) * 4 + gg * 8 + rr;
    const int s_src = sl ^ (jr & 3);
    const int kvoff_sh = jperm * 32 + s_src * 8;       // shorts, per-lane
    const unsigned voffK0 = (unsigned)(kvoff_sh * 2);  // bytes
    const unsigned voffK1 = (unsigned)((kvoff_sh + 64 * 32) * 2);

    // V voffsets (bytes), loop-invariant; j0 folds into the SGPR base
    unsigned voffV[4][4];
    #pragma unroll
    for (int ct = 0; ct < 4; ++ct)
        #pragma unroll
        for (int kt = 0; kt < 4; ++kt)
            voffV[ct][kt] = (unsigned)(((cw0 + ct * 16 + li) * N_ + kt * 32 + g * 8) * 2);

    union PB { unsigned wo[4]; bf16x8 v8; };

    // prologue: stage tile 0 into kT[0]
    {
        const unsigned short* kst0 = kb + kvoff_sh;
        const bf16x8 a0 = *reinterpret_cast<const bf16x8*>(kst0);
        const bf16x8 a1 = *reinterpret_cast<const bf16x8*>(kst0 + 64 * 32);
        *reinterpret_cast<bf16x8*>(&kT[0][t * 8]) = a0;
        *reinterpret_cast<bf16x8*>(&kT[0][2048 + t * 8]) = a1;
    }

    bf16x8 knx0, knx1;

    // QK^T + softmax + publish for tile jj (writes pS[jj&1])
    auto qk_sm_publish = [&](int jj) {
        const char* kbuf = reinterpret_cast<const char*>(&kT[jj & 1][0]);
        f32x4 sT[8];
        #pragma unroll
        for (int h = 0; h < 2; ++h)
            #pragma unroll
            for (int jt = 0; jt < 4; ++jt) {
                const int row = jt * 16 + li;
                const bf16x8 kA = *reinterpret_cast<const bf16x8*>(
                    kbuf + h * 4096 + row * 64 + ((g ^ (row & 3)) << 4));
                sT[h * 4 + jt] = __builtin_amdgcn_mfma_f32_16x16x32_bf16(
                    kA, qf, z4, 0, 0, 0);
            }
        // per-lane max (no shuffles in common path)
        float mx = sT[0][0];
        #pragma unroll
        for (int f8 = 0; f8 < 8; ++f8)
            #pragma unroll
            for (int r = 0; r < 4; ++r) mx = fmaxf(mx, sT[f8][r]);
        float f = 1.0f;
        const int any = __any(mx > m_run + DEFER_THR) ? 1 : 0;
        if (any) {   // rare path: cross-lane (per-query) max + rescale
            float mw = mx;
            mw = fmaxf(mw, __shfl_xor(mw, 16));
            mw = fmaxf(mw, __shfl_xor(mw, 32));
            const float mnew = fmaxf(m_run, mw);
            f = exp2f(m_run - mnew);
            m_run = mnew;
            l_part *= f;
        }
        float sum = 0.f;
        #pragma unroll
        for (int kt = 0; kt < 4; ++kt) {
            float p0[4], p1[4];
            #pragma unroll
            for (int r = 0; r < 4; ++r) {
                p0[r] = exp2f(sT[2 * kt][r] - m_run);
                p1[r] = exp2f(sT[2 * kt + 1][r] - m_run);
                sum += p0[r] + p1[r];
            }
            PB pk2;
            pk2.wo[0] = pack2(p0[0], p0[1]); pk2.wo[1] = pack2(p0[2], p0[3]);
            pk2.wo[2] = pack2(p1[0], p1[1]); pk2.wo[3] = pack2(p1[2], p1[3]);
            *reinterpret_cast<bf16x8*>(&pS[jj & 1][w][kt][l * 8]) = pk2.v8;
        }
        l_part += sum;
        if (l < 16) f_s[jj & 1][w][l] = f;
        if (l == 0) flag_s[jj & 1][w] = any;
    };

    // ---- peel iteration 0: QK/SM/publish only ----
    __syncthreads();
    {
        const unsigned short* sbk = kb + 128 * 32;   // tile 1
        asm volatile("global_load_dwordx4 %0, %2, %4\n\t"
                     "global_load_dwordx4 %1, %3, %4"
                     : "=v"(knx0), "=v"(knx1)
                     : "v"(voffK0), "v"(voffK1), "s"(sbk));
    }
    __builtin_amdgcn_sched_barrier(0);
    qk_sm_publish(0);
    asm volatile("s_waitcnt vmcnt(0)");
    __builtin_amdgcn_sched_barrier(0);
    *reinterpret_cast<bf16x8*>(&kT[1][t * 8]) = knx0;
    *reinterpret_cast<bf16x8*>(&kT[1][2048 + t * 8]) = knx1;

    // ---- main loop: iter jj does QK/SM(jj) and PV(jj-1) ----
    for (int jj = 1; jj < 32; ++jj) {
        __syncthreads();   // kT[jj&1] ready; pS[(jj-1)&1] ready; pS[jj&1] free

        // issue K(jj+1) (2 loads), then V(jj-1) (16 loads)
        {
            const unsigned short* sbk = kb + (size_t)(jj + 1) * 128 * 32;
            asm volatile("global_load_dwordx4 %0, %2, %4\n\t"
                         "global_load_dwordx4 %1, %3, %4"
                         : "=v"(knx0), "=v"(knx1)
                         : "v"(voffK0), "v"(voffK1), "s"(sbk));
        }
        bf16x8 vA[4][4];
        {
            const unsigned short* sbv = vb + (size_t)(jj - 1) * 128;
            #pragma unroll
            for (int ct = 0; ct < 4; ++ct)
                #pragma unroll
                for (int kt = 0; kt < 4; ++kt)
                    asm volatile("global_load_dwordx4 %0, %1, %2"
                                 : "=v"(vA[ct][kt])
                                 : "v"(voffV[ct][kt]), "s"(sbv));
        }
        __builtin_amdgcn_sched_barrier(0);

        qk_sm_publish(jj);

        // K(jj+1) -> kT[(jj+1)&1]  (only the 16 V loads still outstanding)
        asm volatile("s_waitcnt vmcnt(16)");
        __builtin_amdgcn_sched_barrier(0);
        *reinterpret_cast<bf16x8*>(&kT[(jj + 1) & 1][t * 8]) = knx0;
        *reinterpret_cast<bf16x8*>(&kT[(jj + 1) & 1][2048 + t * 8]) = knx1;

        // rescale acc by f(jj-1) (defer-max: usually skipped)
        const int pv = (jj - 1) & 1;
        #pragma unroll
        for (int it = 0; it < 4; ++it) {
            if (flag_s[pv][it]) {
                const float ff = f_s[pv][it][li];
                #pragma unroll
                for (int ct = 0; ct < 4; ++ct) acc[ct][it] *= ff;
            }
        }

        // PV(jj-1): V regs resident, P from pS[pv]
        asm volatile("s_waitcnt vmcnt(0)");
        __builtin_amdgcn_sched_barrier(0);
        __builtin_amdgcn_s_setprio(1);
        #pragma unroll
        for (int kt = 0; kt < 4; ++kt) {
            const bf16x8 pb0 = *reinterpret_cast<const bf16x8*>(&pS[pv][0][kt][l * 8]);
            const bf16x8 pb1 = *reinterpret_cast<const bf16x8*>(&pS[pv][1][kt][l * 8]);
            const bf16x8 pb2 = *reinterpret_cast<const bf16x8*>(&pS[pv][2][kt][l * 8]);
            const bf16x8 pb3 = *reinterpret_cast<const bf16x8*>(&pS[pv][3][kt][l * 8]);
            #pragma unroll
            for (int ct = 0; ct < 4; ++ct) {
                acc[ct][0] = __builtin_amdgcn_mfma_f32_16x16x32_bf16(vA[ct][kt], pb0, acc[ct][0], 0, 0, 0);
                acc[ct][1] = __builtin_amdgcn_mfma_f32_16x16x32_bf16(vA[ct][kt], pb1, acc[ct][1], 0, 0, 0);
                acc[ct][2] = __builtin_amdgcn_mfma_f32_16x16x32_bf16(vA[ct][kt], pb2, acc[ct][2], 0, 0, 0);
                acc[ct][3] = __builtin_amdgcn_mfma_f32_16x16x32_bf16(vA[ct][kt], pb3, acc[ct][3], 0, 0, 0);
            }
        }
        __builtin_amdgcn_s_setprio(0);
    }

    // ---- epilogue: PV(31) ----
    {
        bf16x8 vE[4][4];
        const unsigned short* sbv = vb + (size_t)31 * 128;
        #pragma unroll
        for (int ct = 0; ct < 4; ++ct)
            #pragma unroll
            for (int kt = 0; kt < 4; ++kt)
                asm volatile("global_load_dwordx4 %0, %1, %2"
                             : "=v"(vE[ct][kt])
                             : "v"(voffV[ct][kt]), "s"(sbv));
        __syncthreads();   // pS[1] (tile 31) visible
        #pragma unroll
        for (int it = 0; it < 4; ++it) {
            if (flag_s[1][it]) {
                const float ff = f_s[1][it][li];
                #pragma unroll
                for (int ct = 0; ct < 4; ++ct) acc[ct][it] *= ff;
            }
        }
        asm volatile("s_waitcnt vmcnt(0)");
        __builtin_amdgcn_sched_barrier(0);
        #pragma unroll
        for (int kt = 0; kt < 4; ++kt) {
            const bf16x8 pb0 = *reinterpret_cast<const bf16x8*>(&pS[1][0][kt][l * 8]);
            const bf16x8 pb1 = *reinterpret_cast<const bf16x8*>(&pS[1][1][kt][l * 8]);
            const bf16x8 pb2 = *reinterpret_cast<const bf16x8*>(&pS[1][2][kt][l * 8]);
            const bf16x8 pb3 = *reinterpret_cast<const bf16x8*>(&pS[1][3][kt][l * 8]);
            #pragma unroll
            for (int ct = 0; ct < 4; ++ct) {
                acc[ct][0] = __builtin_amdgcn_mfma_f32_16x16x32_bf16(vE[ct][kt], pb0, acc[ct][0], 0, 0, 0);
                acc[ct][1] = __builtin_amdgcn_mfma_f32_16x16x32_bf16(vE[ct][kt], pb1, acc[ct][1], 0, 0, 0);
                acc[ct][2] = __builtin_amdgcn_mfma_f32_16x16x32_bf16(vE[ct][kt], pb2, acc[ct][2], 0, 0, 0);
                acc[ct][3] = __builtin_amdgcn_mfma_f32_16x16x32_bf16(vE[ct][kt], pb3, acc[ct][3], 0, 0, 0);
            }
        }
    }

    // ---- l: reduce per-lane partials across g once, share across waves ----
    float l_tot = l_part;
    l_tot += __shfl_xor(l_tot, 16);
    l_tot += __shfl_xor(l_tot, 32);
    if (l < 16) l_s[w][l] = l_tot;
    __syncthreads();

    const float gm = gamma[0];
    float linv[4];
    #pragma unroll
    for (int it = 0; it < 4; ++it) linv[it] = 1.0f / l_s[it][li];

    const float* xb2 = x + ((size_t)b * C_) * N_;
    float* ob = out + ((size_t)b * C_) * N_;
    #pragma unroll
    for (int ct = 0; ct < 4; ++ct) {
        #pragma unroll
        for (int r = 0; r < 4; ++r) {
            const int c = cw0 + ct * 16 + 4 * g + r;
            #pragma unroll
            for (int it = 0; it < 4; ++it) {
                const int i = i0 + it * 16 + li;
                const size_t off = (size_t)c * N_ + i;
                ob[off] = gm * acc[ct][it][r] * linv[it] + xb2[off];
            }
        }
    }
}

// ---------------------------------------------------------------------------
// Workspace: q [8][4096][32] | k | v [8][256][4096] bf16 | wbf [320*256] bf16
// = 2 + 2 + 16 + 0.16 MB = ~20.2 MB in d_ws.
// ---------------------------------------------------------------------------
extern "C" void kernel_launch(void* const* d_in, const int* in_sizes, int n_in,
                              void* d_out, int out_size, void* d_ws, size_t ws_size,
                              hipStream_t stream) {
    const float* x     = (const float*)d_in[0];
    const float* Wq    = (const float*)d_in[1];
    const float* bq    = (const float*)d_in[2];
    const float* Wk    = (const float*)d_in[3];
    const float* bk    = (const float*)d_in[4];
    const float* Wv    = (const float*)d_in[5];
    const float* bv    = (const float*)d_in[6];
    const float* gamma = (const float*)d_in[7];
    float* out = (float*)d_out;

    unsigned short* q   = (unsigned short*)d_ws;
    unsigned short* k   = q + (size_t)B_ * N_ * 32;
    unsigned short* v   = k + (size_t)B_ * N_ * 32;
    unsigned short* wbf = v + (size_t)B_ * C_ * N_;

    dim3 grid(N_ / 64, B_);
    w_prep<<<80, 256, 0, stream>>>(Wq, Wk, Wv, wbf);
    qkv_proj_mfma<<<grid, 256, 0, stream>>>(x, wbf, bq, bk, bv, q, k, v);
    attn_mfma<<<512, 256, 0, stream>>>(q, k, v, x, gamma, out);
}

// Round 6
// 179.561 us; speedup vs baseline: 8.9756x; 1.0477x over previous
//
#include <hip/hip_runtime.h>
#include <hip/hip_bf16.h>
#include <math.h>

// Problem constants: x [8,256,64,64] fp32, N = 4096, C = 256, Cqk = 32.
#define B_   8
#define C_   256
#define N_   4096
// 1/sqrt(32) * log2(e): scores computed directly in log2 space -> exp2 only.
#define QSCALE_L2E 0.2550541451582815f
#define DEFER_THR  11.5f   // defer-max threshold in log2 units (~8 nats)

typedef __attribute__((ext_vector_type(8))) short bf16x8;   // 8 bf16 = 4 VGPRs
typedef __attribute__((ext_vector_type(4))) float f32x4;

__device__ __forceinline__ unsigned short bfu(float f) {
    __hip_bfloat16 h = __float2bfloat16(f);
    return __builtin_bit_cast(unsigned short, h);
}
// v_cvt_pk_bf16_f32: lo -> D[15:0], hi -> D[31:16] (single VALU op)
__device__ __forceinline__ unsigned cvtpk(float lo, float hi) {
    unsigned r;
    asm("v_cvt_pk_bf16_f32 %0, %1, %2" : "=v"(r) : "v"(lo), "v"(hi));
    return r;
}

// ---------------------------------------------------------------------------
// Kernel 0: one-time W -> bf16 prep. wbf layout: Wq[32*256] | Wk | Wv[256*256].
// ---------------------------------------------------------------------------
__global__ __launch_bounds__(256) void w_prep(
    const float* __restrict__ Wq, const float* __restrict__ Wk,
    const float* __restrict__ Wv, unsigned short* __restrict__ wbf)
{
    const int i = blockIdx.x * 256 + threadIdx.x;
    const int off = i * 4;
    float4 f;
    if (off < 32 * C_)            f = *reinterpret_cast<const float4*>(Wq + off);
    else if (off < 64 * C_)       f = *reinterpret_cast<const float4*>(Wk + off - 32 * C_);
    else                          f = *reinterpret_cast<const float4*>(Wv + off - 64 * C_);
    ushort4 u;
    u.x = bfu(f.x); u.y = bfu(f.y); u.z = bfu(f.z); u.w = bfu(f.w);
    *reinterpret_cast<ushort4*>(wbf + off) = u;
}

// ---------------------------------------------------------------------------
// Kernel 1: QKV projection via MFMA (unchanged from round 5: LDS-transposed
// coalesced epilogue). Outputs: q,k [b][n][32] bf16 (q pre-scaled), v [b][c][n].
// ---------------------------------------------------------------------------
__global__ __launch_bounds__(256, 2) void qkv_proj_mfma(
    const float* __restrict__ x, const unsigned short* __restrict__ wbf,
    const float* __restrict__ bq, const float* __restrict__ bk,
    const float* __restrict__ bv,
    unsigned short* __restrict__ q, unsigned short* __restrict__ k,
    unsigned short* __restrict__ v)
{
    const int b = blockIdx.y, n0 = blockIdx.x * 64;
    const int t = threadIdx.x;
    const int w = t >> 6, l = t & 63;
    const int li = l & 15, g = l >> 4;

    __shared__ unsigned short xT[64 * 256];     // 32 KB; reused as vS[256][64]
    __shared__ unsigned short qkS[2 * 64 * 32]; // 8 KB

    {
        const int n = t & 63;
        const int cq0 = t >> 6;
        const float* xb = x + ((size_t)b * C_) * N_ + n0 + n;
        #pragma unroll 4
        for (int s = 0; s < 16; ++s) {
            const int cq = cq0 + 4 * s;
            const float f0 = xb[(size_t)(cq * 4 + 0) * N_];
            const float f1 = xb[(size_t)(cq * 4 + 1) * N_];
            const float f2 = xb[(size_t)(cq * 4 + 2) * N_];
            const float f3 = xb[(size_t)(cq * 4 + 3) * N_];
            ushort4 pk;
            pk.x = bfu(f0); pk.y = bfu(f1); pk.z = bfu(f2); pk.w = bfu(f3);
            const int byte = n * 512 + (((cq >> 1) ^ (n & 7)) << 4) + (cq & 1) * 8;
            *reinterpret_cast<ushort4*>(reinterpret_cast<char*>(xT) + byte) = pk;
        }
    }
    __syncthreads();

    const unsigned short* wq_bf = wbf;
    const unsigned short* wk_bf = wbf + 32 * C_;
    const unsigned short* wv_bf = wbf + 64 * C_;

    const unsigned short* wqk_bf = (w < 2) ? wq_bf : wk_bf;
    const float* bqk = (w < 2) ? bq : bk;
    const float qscl = (w < 2) ? QSCALE_L2E : 1.0f;
    const int mt0 = (w & 1) * 2;
    const int ov0 = w * 64;

    f32x4 accv[4][4];
    f32x4 accq[2][2];
    const f32x4 z4 = {0.f, 0.f, 0.f, 0.f};
    #pragma unroll
    for (int a = 0; a < 4; ++a)
        #pragma unroll
        for (int c2 = 0; c2 < 4; ++c2) accv[a][c2] = z4;
    #pragma unroll
    for (int a = 0; a < 2; ++a)
        #pragma unroll
        for (int c2 = 0; c2 < 2; ++c2) accq[a][c2] = z4;

    #pragma unroll 2
    for (int kk = 0; kk < 8; ++kk) {
        bf16x8 xf[4];
        #pragma unroll
        for (int nt = 0; nt < 4; ++nt) {
            const int row = nt * 16 + li;
            const int byte = row * 512 + (((kk * 4 + g) ^ (row & 7)) << 4);
            xf[nt] = *reinterpret_cast<const bf16x8*>(
                reinterpret_cast<const char*>(xT) + byte);
        }
        #pragma unroll
        for (int ot = 0; ot < 4; ++ot) {
            const bf16x8 wV = *reinterpret_cast<const bf16x8*>(
                wv_bf + (size_t)(ov0 + ot * 16 + li) * C_ + kk * 32 + g * 8);
            #pragma unroll
            for (int nt = 0; nt < 4; ++nt)
                accv[nt][ot] = __builtin_amdgcn_mfma_f32_16x16x32_bf16(
                    xf[nt], wV, accv[nt][ot], 0, 0, 0);
        }
        #pragma unroll
        for (int ot = 0; ot < 2; ++ot) {
            const bf16x8 wA = *reinterpret_cast<const bf16x8*>(
                wqk_bf + (size_t)(ot * 16 + li) * C_ + kk * 32 + g * 8);
            #pragma unroll
            for (int m2 = 0; m2 < 2; ++m2)
                accq[ot][m2] = __builtin_amdgcn_mfma_f32_16x16x32_bf16(
                    wA, xf[mt0 + m2], accq[ot][m2], 0, 0, 0);
        }
    }

    __syncthreads();   // xT reads done: reuse as vS

    {
        const int qk = (w < 2) ? 0 : 1;
        #pragma unroll
        for (int ot = 0; ot < 2; ++ot) {
            const int d0 = ot * 16 + 4 * g;
            const float4 b4 = *reinterpret_cast<const float4*>(bqk + d0);
            const int slot = ot * 4 + g;
            #pragma unroll
            for (int m2 = 0; m2 < 2; ++m2) {
                const int n = (mt0 + m2) * 16 + li;
                ushort4 s4;
                s4.x = bfu((accq[ot][m2][0] + b4.x) * qscl);
                s4.y = bfu((accq[ot][m2][1] + b4.y) * qscl);
                s4.z = bfu((accq[ot][m2][2] + b4.z) * qscl);
                s4.w = bfu((accq[ot][m2][3] + b4.w) * qscl);
                const int byte = qk * 4096 + n * 64 + ((slot ^ (n & 7)) << 3);
                *reinterpret_cast<ushort4*>(reinterpret_cast<char*>(qkS) + byte) = s4;
            }
        }
    }
    {
        #pragma unroll
        for (int ot = 0; ot < 4; ++ot) {
            const int o = ov0 + ot * 16 + li;
            const float bias = bv[o];
            #pragma unroll
            for (int nt = 0; nt < 4; ++nt) {
                ushort4 s4;
                s4.x = bfu(accv[nt][ot][0] + bias);
                s4.y = bfu(accv[nt][ot][1] + bias);
                s4.z = bfu(accv[nt][ot][2] + bias);
                s4.w = bfu(accv[nt][ot][3] + bias);
                const int slot = nt * 4 + g;
                const int byte = o * 128 + ((slot ^ (o & 7)) << 3);
                *reinterpret_cast<ushort4*>(reinterpret_cast<char*>(xT) + byte) = s4;
            }
        }
    }
    __syncthreads();

    {
        const char* qks = reinterpret_cast<const char*>(qkS);
        #pragma unroll
        for (int qk = 0; qk < 2; ++qk) {
            const int n = t >> 2, s2 = (t & 3) * 2;
            const int byteA = qk * 4096 + n * 64 + (((s2    ) ^ (n & 7)) << 3);
            const int byteB = qk * 4096 + n * 64 + (((s2 + 1) ^ (n & 7)) << 3);
            const uint2 lo = *reinterpret_cast<const uint2*>(qks + byteA);
            const uint2 hi = *reinterpret_cast<const uint2*>(qks + byteB);
            uint4 val = make_uint4(lo.x, lo.y, hi.x, hi.y);
            unsigned short* dst = (qk == 0) ? q : k;
            *reinterpret_cast<uint4*>(dst + ((size_t)b * N_ + n0) * 32 + t * 8) = val;
        }
    }
    {
        const char* vs = reinterpret_cast<const char*>(xT);
        #pragma unroll
        for (int p2 = 0; p2 < 8; ++p2) {
            const int o = p2 * 32 + (t >> 3);
            const int s2 = (t & 7) * 2;
            const int byteA = o * 128 + (((s2    ) ^ (o & 7)) << 3);
            const int byteB = o * 128 + (((s2 + 1) ^ (o & 7)) << 3);
            const uint2 lo = *reinterpret_cast<const uint2*>(vs + byteA);
            const uint2 hi = *reinterpret_cast<const uint2*>(vs + byteB);
            uint4 val = make_uint4(lo.x, lo.y, hi.x, hi.y);
            *reinterpret_cast<uint4*>(v + ((size_t)b * C_ + o) * N_ + n0 + (t & 7) * 8) = val;
        }
    }
}

// ---------------------------------------------------------------------------
// Kernel 2: flash attention. grid 512 1-D (b = id&7 -> XCD-local), 4 waves.
// Per 128-j iteration (ONE barrier):
//   [sync] -> rescale(jj-1) -> QK(jj) MFMA -> vmcnt(0)[V(jj-1)] ->
//   PV(jj-1) 64-MFMA cluster (setprio) -> issue K(jj+2-frame)/V(jj) loads ->
//   softmax(jj) VALU (overlaps PV in the matrix pipe) -> publish pS ->
//   vmcnt(16)[K only] -> kT write.
// Counted vmcnt; "memory"-clobbered waits + sched_barrier(0) fences (rule #18
// and the ds_write-hoist hazard). Softmax: tree max/sum, raw v_exp_f32,
// v_cvt_pk_bf16_f32 packing. V consumed from regs loaded one full phase prior.
// ---------------------------------------------------------------------------
__global__ __launch_bounds__(256, 2) void attn_mfma(
    const unsigned short* __restrict__ q, const unsigned short* __restrict__ k,
    const unsigned short* __restrict__ v,
    const float* __restrict__ x, const float* __restrict__ gamma,
    float* __restrict__ out)
{
    const int id = blockIdx.x;
    const int b = id & 7;                 // batch == XCD
    const int i0 = (id >> 3) * 64;
    const int t = threadIdx.x;
    const int w = t >> 6, l = t & 63;
    const int li = l & 15, g = l >> 4;
    const int cw0 = w * 64;

    __shared__ unsigned short kT[2][128 * 32];      // 16 KB double-buffered K
    __shared__ unsigned short pS[2][4][4][64 * 8];  // 32 KB double-buffered P
    __shared__ float f_s[2][4][16];
    __shared__ int   flag_s[2][4];
    __shared__ float l_s[4][16];

    const unsigned short* qb = q + (size_t)b * N_ * 32;
    const unsigned short* kb = k + (size_t)b * N_ * 32;
    const unsigned short* vb = v + ((size_t)b * C_) * N_;

    const bf16x8 qf = *reinterpret_cast<const bf16x8*>(
        qb + (size_t)(i0 + w * 16 + li) * 32 + g * 8);

    f32x4 acc[4][4];   // [ct][it] : O^T[c][i]
    const f32x4 z4 = {0.f, 0.f, 0.f, 0.f};
    #pragma unroll
    for (int a = 0; a < 4; ++a)
        #pragma unroll
        for (int c2 = 0; c2 < 4; ++c2) acc[a][c2] = z4;

    float m_run = -3.0e38f;
    float l_part = 0.f;

    // K staging constants (rows permuted so S^T D-frag rows = PV-B-frag j's)
    const int jr = t >> 2, sl = t & 3;
    const int jt_s = jr >> 4, gg = (jr >> 2) & 3, rr = jr & 3;
    const int jperm = (jt_s >> 1) * 32 + (jt_s & 1) * 4 + gg * 8 + rr;
    const int s_src = sl ^ (jr & 3);
    const int kvoff_sh = jperm * 32 + s_src * 8;
    const unsigned voffK0 = (unsigned)(kvoff_sh * 2);
    const unsigned voffK1 = (unsigned)((kvoff_sh + 64 * 32) * 2);

    unsigned voffV[4][4];
    #pragma unroll
    for (int ct = 0; ct < 4; ++ct)
        #pragma unroll
        for (int kt = 0; kt < 4; ++kt)
            voffV[ct][kt] = (unsigned)(((cw0 + ct * 16 + li) * N_ + kt * 32 + g * 8) * 2);

    union PB { unsigned wo[4]; bf16x8 v8; };

    // prologue: stage tile 0 into kT[0]
    {
        const unsigned short* kst0 = kb + kvoff_sh;
        const bf16x8 a0 = *reinterpret_cast<const bf16x8*>(kst0);
        const bf16x8 a1 = *reinterpret_cast<const bf16x8*>(kst0 + 64 * 32);
        *reinterpret_cast<bf16x8*>(&kT[0][t * 8]) = a0;
        *reinterpret_cast<bf16x8*>(&kT[0][2048 + t * 8]) = a1;
    }

    bf16x8 knx0, knx1;
    bf16x8 vA[4][4];

    // ---- softmax + publish for tile jj; p computed in-place over sT ----
    auto softmax_publish = [&](int cur, f32x4* sT) {
        float fm[8];
        #pragma unroll
        for (int f8 = 0; f8 < 8; ++f8)
            fm[f8] = fmaxf(fmaxf(sT[f8][0], sT[f8][1]), fmaxf(sT[f8][2], sT[f8][3]));
        float mx = fmaxf(fmaxf(fmaxf(fm[0], fm[1]), fmaxf(fm[2], fm[3])),
                         fmaxf(fmaxf(fm[4], fm[5]), fmaxf(fm[6], fm[7])));
        float f = 1.0f;
        const int any = __any(mx > m_run + DEFER_THR) ? 1 : 0;
        if (any) {
            float mw = fmaxf(mx, __shfl_xor(mx, 16));
            mw = fmaxf(mw, __shfl_xor(mw, 32));
            const float mnew = fmaxf(m_run, mw);
            f = __builtin_amdgcn_exp2f(m_run - mnew);
            m_run = mnew;
            l_part *= f;
        }
        #pragma unroll
        for (int f8 = 0; f8 < 8; ++f8)
            #pragma unroll
            for (int r = 0; r < 4; ++r)
                sT[f8][r] = __builtin_amdgcn_exp2f(sT[f8][r] - m_run);
        const f32x4 sv = ((sT[0] + sT[1]) + (sT[2] + sT[3]))
                       + ((sT[4] + sT[5]) + (sT[6] + sT[7]));
        l_part += (sv[0] + sv[1]) + (sv[2] + sv[3]);
        #pragma unroll
        for (int kt = 0; kt < 4; ++kt) {
            PB pk2;
            pk2.wo[0] = cvtpk(sT[2 * kt][0],     sT[2 * kt][1]);
            pk2.wo[1] = cvtpk(sT[2 * kt][2],     sT[2 * kt][3]);
            pk2.wo[2] = cvtpk(sT[2 * kt + 1][0], sT[2 * kt + 1][1]);
            pk2.wo[3] = cvtpk(sT[2 * kt + 1][2], sT[2 * kt + 1][3]);
            *reinterpret_cast<bf16x8*>(&pS[cur][w][kt][l * 8]) = pk2.v8;
        }
        if (l < 16) f_s[cur][w][l] = f;
        if (l == 0) flag_s[cur][w] = any;
    };

    __syncthreads();

    // ---- peel jj = 0: issue K(1)+V(0), QK(0), softmax(0), kT[1] ----
    {
        const unsigned short* sbk = kb + 128 * 32;
        asm volatile("global_load_dwordx4 %0, %2, %4\n\t"
                     "global_load_dwordx4 %1, %3, %4"
                     : "=v"(knx0), "=v"(knx1)
                     : "v"(voffK0), "v"(voffK1), "s"(sbk));
        const unsigned short* sbv = vb;
        #pragma unroll
        for (int ct = 0; ct < 4; ++ct)
            #pragma unroll
            for (int kt = 0; kt < 4; ++kt)
                asm volatile("global_load_dwordx4 %0, %1, %2"
                             : "=v"(vA[ct][kt])
                             : "v"(voffV[ct][kt]), "s"(sbv));
        __builtin_amdgcn_sched_barrier(0);

        f32x4 sT[8];
        const char* kbuf = reinterpret_cast<const char*>(&kT[0][0]);
        #pragma unroll
        for (int f8 = 0; f8 < 8; ++f8) {
            const int h = f8 >> 2, jt = f8 & 3;
            const int row = jt * 16 + li;
            const bf16x8 kA = *reinterpret_cast<const bf16x8*>(
                kbuf + h * 4096 + row * 64 + ((g ^ (row & 3)) << 4));
            sT[f8] = __builtin_amdgcn_mfma_f32_16x16x32_bf16(kA, qf, z4, 0, 0, 0);
        }
        softmax_publish(0, sT);

        asm volatile("s_waitcnt vmcnt(16)" ::: "memory");
        __builtin_amdgcn_sched_barrier(0);
        *reinterpret_cast<bf16x8*>(&kT[1][t * 8]) = knx0;
        *reinterpret_cast<bf16x8*>(&kT[1][2048 + t * 8]) = knx1;
    }

    // ---- main loop: iter jj does QK/SM(jj), PV(jj-1), prefetch K/V ----
    for (int jj = 1; jj < 32; ++jj) {
        __syncthreads();   // kT[jj&1], pS[(jj-1)&1], f/flag[(jj-1)&1] visible
        const int pv = (jj - 1) & 1;
        const int cur = jj & 1;

        // rescale acc (defer-max: usually skipped)
        #pragma unroll
        for (int it = 0; it < 4; ++it) {
            if (flag_s[pv][it]) {
                const float ff = f_s[pv][it][li];
                #pragma unroll
                for (int ct = 0; ct < 4; ++ct) acc[ct][it] *= ff;
            }
        }

        // QK(jj): 8 MFMA enter the pipe first -> sT ready early for softmax
        f32x4 sT[8];
        {
            const char* kbuf = reinterpret_cast<const char*>(&kT[cur][0]);
            #pragma unroll
            for (int f8 = 0; f8 < 8; ++f8) {
                const int h = f8 >> 2, jt = f8 & 3;
                const int row = jt * 16 + li;
                const bf16x8 kA = *reinterpret_cast<const bf16x8*>(
                    kbuf + h * 4096 + row * 64 + ((g ^ (row & 3)) << 4));
                sT[f8] = __builtin_amdgcn_mfma_f32_16x16x32_bf16(kA, qf, z4, 0, 0, 0);
            }
        }

        // V(jj-1) fully landed (issued one phase ago; only V outstanding)
        asm volatile("s_waitcnt vmcnt(0)" ::: "memory");
        __builtin_amdgcn_sched_barrier(0);

        // PV(jj-1): 64-MFMA cluster
        __builtin_amdgcn_s_setprio(1);
        #pragma unroll
        for (int kt = 0; kt < 4; ++kt) {
            const bf16x8 pb0 = *reinterpret_cast<const bf16x8*>(&pS[pv][0][kt][l * 8]);
            const bf16x8 pb1 = *reinterpret_cast<const bf16x8*>(&pS[pv][1][kt][l * 8]);
            const bf16x8 pb2 = *reinterpret_cast<const bf16x8*>(&pS[pv][2][kt][l * 8]);
            const bf16x8 pb3 = *reinterpret_cast<const bf16x8*>(&pS[pv][3][kt][l * 8]);
            #pragma unroll
            for (int ct = 0; ct < 4; ++ct) {
                acc[ct][0] = __builtin_amdgcn_mfma_f32_16x16x32_bf16(vA[ct][kt], pb0, acc[ct][0], 0, 0, 0);
                acc[ct][1] = __builtin_amdgcn_mfma_f32_16x16x32_bf16(vA[ct][kt], pb1, acc[ct][1], 0, 0, 0);
                acc[ct][2] = __builtin_amdgcn_mfma_f32_16x16x32_bf16(vA[ct][kt], pb2, acc[ct][2], 0, 0, 0);
                acc[ct][3] = __builtin_amdgcn_mfma_f32_16x16x32_bf16(vA[ct][kt], pb3, acc[ct][3], 0, 0, 0);
            }
        }
        __builtin_amdgcn_s_setprio(0);
        __builtin_amdgcn_sched_barrier(0);

        // issue K(jj+1) FIRST (so vmcnt(16) releases it), then V(jj)
        {
            const unsigned short* sbk = kb + (size_t)((jj == 31) ? 0 : (jj + 1)) * 128 * 32;
            asm volatile("global_load_dwordx4 %0, %2, %4\n\t"
                         "global_load_dwordx4 %1, %3, %4"
                         : "=v"(knx0), "=v"(knx1)
                         : "v"(voffK0), "v"(voffK1), "s"(sbk));
            const unsigned short* sbv = vb + (size_t)jj * 128;
            #pragma unroll
            for (int ct = 0; ct < 4; ++ct)
                #pragma unroll
                for (int kt = 0; kt < 4; ++kt)
                    asm volatile("global_load_dwordx4 %0, %1, %2"
                                 : "=v"(vA[ct][kt])
                                 : "v"(voffV[ct][kt]), "s"(sbv));
        }
        __builtin_amdgcn_sched_barrier(0);

        // softmax(jj): VALU overlaps the PV MFMA cluster in the pipe
        softmax_publish(cur, sT);

        // kT[(jj+1)&1] write: K done at vmcnt(16) (V(jj) 16 still in flight)
        asm volatile("s_waitcnt vmcnt(16)" ::: "memory");
        __builtin_amdgcn_sched_barrier(0);
        *reinterpret_cast<bf16x8*>(&kT[pv][t * 8]) = knx0;          // (jj+1)&1 == pv
        *reinterpret_cast<bf16x8*>(&kT[pv][2048 + t * 8]) = knx1;
    }

    // ---- epilogue: PV(31) with pS[1], V(31) in vA ----
    __syncthreads();
    #pragma unroll
    for (int it = 0; it < 4; ++it) {
        if (flag_s[1][it]) {
            const float ff = f_s[1][it][li];
            #pragma unroll
            for (int ct = 0; ct < 4; ++ct) acc[ct][it] *= ff;
        }
    }
    asm volatile("s_waitcnt vmcnt(0)" ::: "memory");
    __builtin_amdgcn_sched_barrier(0);
    #pragma unroll
    for (int kt = 0; kt < 4; ++kt) {
        const bf16x8 pb0 = *reinterpret_cast<const bf16x8*>(&pS[1][0][kt][l * 8]);
        const bf16x8 pb1 = *reinterpret_cast<const bf16x8*>(&pS[1][1][kt][l * 8]);
        const bf16x8 pb2 = *reinterpret_cast<const bf16x8*>(&pS[1][2][kt][l * 8]);
        const bf16x8 pb3 = *reinterpret_cast<const bf16x8*>(&pS[1][3][kt][l * 8]);
        #pragma unroll
        for (int ct = 0; ct < 4; ++ct) {
            acc[ct][0] = __builtin_amdgcn_mfma_f32_16x16x32_bf16(vA[ct][kt], pb0, acc[ct][0], 0, 0, 0);
            acc[ct][1] = __builtin_amdgcn_mfma_f32_16x16x32_bf16(vA[ct][kt], pb1, acc[ct][1], 0, 0, 0);
            acc[ct][2] = __builtin_amdgcn_mfma_f32_16x16x32_bf16(vA[ct][kt], pb2, acc[ct][2], 0, 0, 0);
            acc[ct][3] = __builtin_amdgcn_mfma_f32_16x16x32_bf16(vA[ct][kt], pb3, acc[ct][3], 0, 0, 0);
        }
    }

    // ---- l: reduce per-lane partials across g, share across waves ----
    float l_tot = l_part;
    l_tot += __shfl_xor(l_tot, 16);
    l_tot += __shfl_xor(l_tot, 32);
    if (l < 16) l_s[w][l] = l_tot;
    __syncthreads();

    const float gm = gamma[0];
    float linv[4];
    #pragma unroll
    for (int it = 0; it < 4; ++it) linv[it] = 1.0f / l_s[it][li];

    const float* xb2 = x + ((size_t)b * C_) * N_;
    float* ob = out + ((size_t)b * C_) * N_;
    #pragma unroll
    for (int ct = 0; ct < 4; ++ct) {
        #pragma unroll
        for (int r = 0; r < 4; ++r) {
            const int c = cw0 + ct * 16 + 4 * g + r;
            #pragma unroll
            for (int it = 0; it < 4; ++it) {
                const int i = i0 + it * 16 + li;
                const size_t off = (size_t)c * N_ + i;
                ob[off] = gm * acc[ct][it][r] * linv[it] + xb2[off];
            }
        }
    }
}

// ---------------------------------------------------------------------------
// Workspace: q [8][4096][32] | k | v [8][256][4096] bf16 | wbf [320*256] bf16
// = 2 + 2 + 16 + 0.16 MB = ~20.2 MB in d_ws.
// ---------------------------------------------------------------------------
extern "C" void kernel_launch(void* const* d_in, const int* in_sizes, int n_in,
                              void* d_out, int out_size, void* d_ws, size_t ws_size,
                              hipStream_t stream) {
    const float* x     = (const float*)d_in[0];
    const float* Wq    = (const float*)d_in[1];
    const float* bq    = (const float*)d_in[2];
    const float* Wk    = (const float*)d_in[3];
    const float* bk    = (const float*)d_in[4];
    const float* Wv    = (const float*)d_in[5];
    const float* bv    = (const float*)d_in[6];
    const float* gamma = (const float*)d_in[7];
    float* out = (float*)d_out;

    unsigned short* q   = (unsigned short*)d_ws;
    unsigned short* k   = q + (size_t)B_ * N_ * 32;
    unsigned short* v   = k + (size_t)B_ * N_ * 32;
    unsigned short* wbf = v + (size_t)B_ * C_ * N_;

    dim3 grid(N_ / 64, B_);
    w_prep<<<80, 256, 0, stream>>>(Wq, Wk, Wv, wbf);
    qkv_proj_mfma<<<grid, 256, 0, stream>>>(x, wbf, bq, bk, bv, q, k, v);
    attn_mfma<<<512, 256, 0, stream>>>(q, k, v, x, gamma, out);
}